// Round 5
// baseline (277.846 us; speedup 1.0000x reference)
//
#include <hip/hip_runtime.h>
#include <math.h>

// ---------------- problem constants ----------------
constexpr int BATCH  = 2;
constexpr int CDIM   = 96;    // model dim
constexpr int HH     = 56;
constexpr int WW     = 56;
constexpr int LL     = HH * WW;          // 3136
constexpr int DIN    = 192;              // d_inner
constexpr int NK     = 4;                // directions
constexpr int NST    = 16;               // d_state
constexpr int RNK    = 6;                // dt_rank
constexpr int EPROJ  = RNK + 2 * NST;    // 38
constexpr int SCH    = 64;               // steps per scan chunk
constexpr int NCH    = LL / SCH;         // 49 chunks
constexpr int CGRP   = DIN / 16;         // 12 channel-groups of 16

// workspace layout (floats)
constexpr size_t SZ_PX   = (size_t)BATCH * LL * DIN;        // 1,204,224
constexpr size_t OFF_XP  = 0;                               // xp; reused as Pbuf
constexpr size_t OFF_Z   = OFF_XP + SZ_PX;
constexpr size_t OFF_XI  = OFF_Z  + SZ_PX;
constexpr size_t OFF_DR  = OFF_XI + SZ_PX;                  // dr: [kb][L][8]
constexpr size_t SZ_DR   = (size_t)NK * BATCH * LL * 8;
constexpr size_t OFF_B   = OFF_DR + SZ_DR;                  // B: K*B*L*16
constexpr size_t SZ_BC   = (size_t)NK * BATCH * LL * NST;
constexpr size_t OFF_C   = OFF_B + SZ_BC;
constexpr size_t OFF_Y   = OFF_C + SZ_BC;                   // ysum: B*L*192
constexpr size_t SZ_HS   = (size_t)NK * BATCH * NCH * DIN * NST;
constexpr size_t OFF_HE  = OFF_Y + SZ_PX;                   // h_end per chunk
constexpr size_t OFF_HI  = OFF_HE + SZ_HS;                  // h_in  per chunk
constexpr size_t OFF_WT  = OFF_HI + SZ_HS;                  // Wt: [k][e][d]
constexpr size_t SZ_WT   = (size_t)NK * EPROJ * DIN;        // 29,184

__device__ __forceinline__ float silu(float v) {
    return v / (1.0f + __expf(-v));
}

__device__ __forceinline__ float softplus_f(float x) {
    return (x > 20.0f) ? x : __logf(1.0f + __expf(x));
}

// full 16-lane-row sum via DPP row rotations (VALU only, no LDS pipe).
__device__ __forceinline__ float row_reduce16(float p) {
    p += __int_as_float(__builtin_amdgcn_update_dpp(0, __float_as_int(p), 0x128, 0xf, 0xf, true));
    p += __int_as_float(__builtin_amdgcn_update_dpp(0, __float_as_int(p), 0x124, 0xf, 0xf, true));
    p += __int_as_float(__builtin_amdgcn_update_dpp(0, __float_as_int(p), 0x122, 0xf, 0xf, true));
    p += __int_as_float(__builtin_amdgcn_update_dpp(0, __float_as_int(p), 0x121, 0xf, 0xf, true));
    return p;
}

// direction k, sequence position l -> row-major spatial index
__device__ __forceinline__ int seq_to_lr(int k, int l) {
    int q = l / WW;
    int r = l - q * WW;
    if (k == 0) return l;
    if (k == 1) return q * WW + (WW - 1 - r);
    if (k == 2) return r * WW + q;
    return (WW - 1 - r) * WW + q;
}

// direction k, row-major spatial index s -> sequence position (inverse map)
__device__ __forceinline__ int spatial_to_seq(int k, int s) {
    int h = s / WW;
    int w = s - h * WW;
    if (k == 0) return s;
    if (k == 1) return h * WW + (WW - 1 - w);
    if (k == 2) return w * WW + h;
    return w * WW + (WW - 1 - h);
}

// chunk-summary index: [c][kb][d][n]
__device__ __forceinline__ size_t hs_idx(int c, int kb, int d, int n) {
    return ((size_t)(c * (NK * BATCH) + kb) * DIN + d) * NST + n;
}

// ---------------- kernel 0: transpose W_xproj -> Wt[k][e][d] ----------------
__global__ __launch_bounds__(256) void k_wt(
        const float* __restrict__ W_xproj, float* __restrict__ Wt) {
    int i = blockIdx.x * 256 + threadIdx.x;
    if (i >= NK * DIN * EPROJ) return;
    int k = i / (DIN * EPROJ);
    int r = i % (DIN * EPROJ);
    int d = r / EPROJ;
    int e = r % EPROJ;
    Wt[((size_t)k * EPROJ + e) * DIN + d] = W_xproj[i];
}

// ---------------- kernel 1: in-projection (x^T @ W_in -> xp, z) --------------
constexpr int K1_PIX = 8;
__global__ __launch_bounds__(384) void k_inproj(
        const float* __restrict__ x, const float* __restrict__ W_in,
        float* __restrict__ xp, float* __restrict__ z) {
    __shared__ float sx[K1_PIX][100];   // padded to break bank conflicts
    int gp0 = blockIdx.x * K1_PIX;      // global pixel = b*LL + l
    int t   = threadIdx.x;
    int b   = gp0 / LL;
    int l0  = gp0 - b * LL;
    for (int i = t; i < K1_PIX * CDIM; i += 384) {
        int p = i % K1_PIX;
        int c = i / K1_PIX;
        sx[p][c] = x[((size_t)(b * CDIM + c)) * LL + l0 + p];
    }
    __syncthreads();
    int e = t;                          // 0..383 output feature
    float acc[K1_PIX];
#pragma unroll
    for (int p = 0; p < K1_PIX; p++) acc[p] = 0.0f;
    for (int c = 0; c < CDIM; c++) {
        float w = W_in[c * (2 * DIN) + e];
#pragma unroll
        for (int p = 0; p < K1_PIX; p++) acc[p] = fmaf(sx[p][c], w, acc[p]);
    }
    if (e < DIN) {
#pragma unroll
        for (int p = 0; p < K1_PIX; p++)
            xp[((size_t)(gp0 + p)) * DIN + e] = acc[p];
    } else {
        int e2 = e - DIN;
#pragma unroll
        for (int p = 0; p < K1_PIX; p++)
            z[((size_t)(gp0 + p)) * DIN + e2] = acc[p];
    }
}

// ---------------- kernel 2: depthwise conv 3x3 + bias + SiLU ----------------
__global__ __launch_bounds__(192) void k_conv(
        const float* __restrict__ xp, const float* __restrict__ Wc,
        const float* __restrict__ bc, float* __restrict__ xi) {
    int gp = blockIdx.x;
    int d  = threadIdx.x;
    int b  = gp / LL;
    int l  = gp - b * LL;
    int h  = l / WW;
    int w  = l - h * WW;
    float acc = bc[d];
#pragma unroll
    for (int dy = -1; dy <= 1; dy++) {
        int hh = h + dy;
        if (hh < 0 || hh >= HH) continue;
#pragma unroll
        for (int dx = -1; dx <= 1; dx++) {
            int ww = w + dx;
            if (ww < 0 || ww >= WW) continue;
            acc = fmaf(xp[((size_t)b * LL + hh * WW + ww) * DIN + d],
                       Wc[d * 9 + (dy + 1) * 3 + (dx + 1)], acc);
        }
    }
    xi[(size_t)gp * DIN + d] = silu(acc);
}

// ------- kernel 3: x-proj -> dr (rank-6), B, C; ysum = xi*sum_k(Ds) ----------
// e-pair register tiling + float4 LDS/global reads. Delta is NOT materialized;
// scan kernels recompute it from dr.
constexpr int K3_PIX = 16;
__global__ __launch_bounds__(256) void k_xproj(
        const float* __restrict__ xi, const float* __restrict__ Wt,
        const float* __restrict__ Ds,
        float* __restrict__ drbuf, float* __restrict__ Bbuf,
        float* __restrict__ Cbuf, float* __restrict__ ysum) {
    __shared__ float4 sv[K3_PIX][48];   // xi tile, float4 over d
    int k   = blockIdx.y;
    int gp0 = blockIdx.x * K3_PIX;
    int b   = gp0 / LL;
    int l0  = gp0 - b * LL;
    int t   = threadIdx.x;
    const float4* xin = (const float4*)(xi + (size_t)gp0 * DIN);
    for (int i = t; i < K3_PIX * 48; i += 256)
        sv[i / 48][i % 48] = xin[i];
    __syncthreads();
    if (k == 0) {
        const float* svf = (const float*)sv;
        for (int i = t; i < K3_PIX * DIN; i += 256) {
            int d = i % DIN;
            float dsum = Ds[d] + Ds[DIN + d] + Ds[2 * DIN + d] + Ds[3 * DIN + d];
            ysum[(size_t)gp0 * DIN + i] = svf[i] * dsum;
        }
    }
    // 16 px * 19 e-pairs = 304 items
    for (int item = t; item < K3_PIX * 19; item += 256) {
        int p  = item / 19;
        int e0 = 2 * (item % 19);
        const float4* w0 = (const float4*)(Wt + ((size_t)k * EPROJ + e0) * DIN);
        const float4* w1 = w0 + 48;
        float a0 = 0.0f, a1 = 0.0f;
#pragma unroll 8
        for (int j = 0; j < 48; j++) {
            float4 vv = sv[p][j];
            float4 wa = w0[j];
            float4 wb = w1[j];
            a0 = fmaf(vv.x, wa.x, a0); a0 = fmaf(vv.y, wa.y, a0);
            a0 = fmaf(vv.z, wa.z, a0); a0 = fmaf(vv.w, wa.w, a0);
            a1 = fmaf(vv.x, wb.x, a1); a1 = fmaf(vv.y, wb.y, a1);
            a1 = fmaf(vv.z, wb.z, a1); a1 = fmaf(vv.w, wb.w, a1);
        }
        int ls = spatial_to_seq(k, l0 + p);
        size_t kb   = (size_t)(k * BATCH + b);
        size_t b8   = (kb * LL + ls) * 8;
        size_t b16  = (kb * LL + ls) * NST;
        // pairs never straddle the dr/B (6) or B/C (22) boundary (both even)
        if (e0 < RNK) {
            drbuf[b8 + e0] = a0; drbuf[b8 + e0 + 1] = a1;
        } else if (e0 < RNK + NST) {
            Bbuf[b16 + e0 - RNK] = a0; Bbuf[b16 + e0 - RNK + 1] = a1;
        } else {
            Cbuf[b16 + e0 - RNK - NST] = a0; Cbuf[b16 + e0 - RNK - NST + 1] = a1;
        }
    }
}

// -------- kernel 4a: chunk-local scan -> per-chunk summary (P, h_end) --------
__global__ __launch_bounds__(256) void k_scanA(
        const float* __restrict__ xi, const float* __restrict__ drbuf,
        const float* __restrict__ Bbuf, const float* __restrict__ A_logs,
        const float* __restrict__ W_dt, const float* __restrict__ b_dt,
        float* __restrict__ Pbuf, float* __restrict__ hend) {
    __shared__ float2 sDU[SCH][16];   // {delta, delta*u}
    __shared__ float  sB1[SCH][16];
    int c   = blockIdx.x;
    int blk = blockIdx.y;
    int k   = blk / (BATCH * CGRP);
    int rem = blk % (BATCH * CGRP);
    int b   = rem / CGRP;
    int cg  = rem % CGRP;
    int d0  = cg * 16;
    int t    = threadIdx.x;
    int lane = t & 63, wave = t >> 6;
    int grp  = lane >> 4, n = lane & 15;
    int ch   = wave * 4 + grp;
    int d    = d0 + ch;
    float A = -__expf(A_logs[((size_t)(k * DIN + d)) * NST + n]);
    size_t kb = (size_t)(k * BATCH + b);
    const float* drp = drbuf + kb * LL * 8;
    const float* bp  = Bbuf  + kb * LL * NST;
    const float* up  = xi    + (size_t)b * LL * DIN;
    // delta weights for this thread's staging column (cc = t&15, const per iter)
    int dloc = d0 + (t & 15);
    float bb = b_dt[k * DIN + dloc];
    float w0 = W_dt[((size_t)k * RNK + 0) * DIN + dloc];
    float w1 = W_dt[((size_t)k * RNK + 1) * DIN + dloc];
    float w2 = W_dt[((size_t)k * RNK + 2) * DIN + dloc];
    float w3 = W_dt[((size_t)k * RNK + 3) * DIN + dloc];
    float w4 = W_dt[((size_t)k * RNK + 4) * DIN + dloc];
    float w5 = W_dt[((size_t)k * RNK + 5) * DIN + dloc];
    int l0 = c * SCH;
    for (int i = t; i < SCH * 16; i += 256) {
        int s = i >> 4, cc = i & 15;
        int l = l0 + s;
        int lr = seq_to_lr(k, l);
        float4 r03 = *(const float4*)(drp + (size_t)l * 8);
        float2 r45 = *(const float2*)(drp + (size_t)l * 8 + 4);
        float raw = bb;
        raw = fmaf(r03.x, w0, raw); raw = fmaf(r03.y, w1, raw);
        raw = fmaf(r03.z, w2, raw); raw = fmaf(r03.w, w3, raw);
        raw = fmaf(r45.x, w4, raw); raw = fmaf(r45.y, w5, raw);
        float dlt = softplus_f(raw);
        float u = up[(size_t)lr * DIN + d0 + cc];
        sDU[s][cc] = make_float2(dlt, dlt * u);
        sB1[s][cc] = bp[(size_t)l * NST + cc];
    }
    __syncthreads();
    float h = 0.0f, P = 1.0f;
#pragma unroll 8
    for (int s = 0; s < SCH; s++) {
        float2 du = sDU[s][ch];
        float dA  = __expf(du.x * A);
        h = fmaf(dA, h, du.y * sB1[s][n]);
        P *= dA;
    }
    size_t idx = hs_idx(c, (int)kb, d, n);
    Pbuf[idx] = P;
    hend[idx] = h;
}

// -------- kernel 4b: sequential combine over 49 chunk summaries --------------
__global__ __launch_bounds__(256) void k_scanB(
        const float* __restrict__ Pbuf, const float* __restrict__ hend,
        float* __restrict__ hin) {
    int tid = blockIdx.x * 256 + threadIdx.x;       // over K*B*DIN*NST = 24576
    int kb  = tid / (DIN * NST);
    int dn  = tid % (DIN * NST);
    float h = 0.0f;
    for (int c = 0; c < NCH; c++) {
        size_t idx = ((size_t)(c * (NK * BATCH) + kb)) * (DIN * NST) + dn;
        hin[idx] = h;
        h = fmaf(Pbuf[idx], h, hend[idx]);
    }
}

// -------- kernel 4c: chunk-local scan with true h_in; emit y -----------------
__global__ __launch_bounds__(256) void k_scanC(
        const float* __restrict__ xi, const float* __restrict__ drbuf,
        const float* __restrict__ Bbuf, const float* __restrict__ Cbuf,
        const float* __restrict__ A_logs, const float* __restrict__ W_dt,
        const float* __restrict__ b_dt, const float* __restrict__ hin,
        float* __restrict__ ysum) {
    __shared__ float2 sDU[SCH][16];   // {delta, delta*u}
    __shared__ float2 sBC[SCH][16];   // {B, C}
    __shared__ float  sY[SCH][16];
    int c   = blockIdx.x;
    int blk = blockIdx.y;
    int k   = blk / (BATCH * CGRP);
    int rem = blk % (BATCH * CGRP);
    int b   = rem / CGRP;
    int cg  = rem % CGRP;
    int d0  = cg * 16;
    int t    = threadIdx.x;
    int lane = t & 63, wave = t >> 6;
    int grp  = lane >> 4, n = lane & 15;
    int ch   = wave * 4 + grp;
    int d    = d0 + ch;
    float A = -__expf(A_logs[((size_t)(k * DIN + d)) * NST + n]);
    size_t kb = (size_t)(k * BATCH + b);
    const float* drp = drbuf + kb * LL * 8;
    const float* bp  = Bbuf  + kb * LL * NST;
    const float* cp  = Cbuf  + kb * LL * NST;
    const float* up  = xi    + (size_t)b * LL * DIN;
    float*       yp  = ysum  + (size_t)b * LL * DIN;
    int dloc = d0 + (t & 15);
    float bb = b_dt[k * DIN + dloc];
    float w0 = W_dt[((size_t)k * RNK + 0) * DIN + dloc];
    float w1 = W_dt[((size_t)k * RNK + 1) * DIN + dloc];
    float w2 = W_dt[((size_t)k * RNK + 2) * DIN + dloc];
    float w3 = W_dt[((size_t)k * RNK + 3) * DIN + dloc];
    float w4 = W_dt[((size_t)k * RNK + 4) * DIN + dloc];
    float w5 = W_dt[((size_t)k * RNK + 5) * DIN + dloc];
    int l0 = c * SCH;
    for (int i = t; i < SCH * 16; i += 256) {
        int s = i >> 4, cc = i & 15;
        int l = l0 + s;
        int lr = seq_to_lr(k, l);
        float4 r03 = *(const float4*)(drp + (size_t)l * 8);
        float2 r45 = *(const float2*)(drp + (size_t)l * 8 + 4);
        float raw = bb;
        raw = fmaf(r03.x, w0, raw); raw = fmaf(r03.y, w1, raw);
        raw = fmaf(r03.z, w2, raw); raw = fmaf(r03.w, w3, raw);
        raw = fmaf(r45.x, w4, raw); raw = fmaf(r45.y, w5, raw);
        float dlt = softplus_f(raw);
        float u = up[(size_t)lr * DIN + d0 + cc];
        sDU[s][cc] = make_float2(dlt, dlt * u);
        sBC[s][cc] = make_float2(bp[(size_t)l * NST + cc],
                                 cp[(size_t)l * NST + cc]);
    }
    float h = hin[hs_idx(c, (int)kb, d, n)];
    __syncthreads();
#pragma unroll 4
    for (int s = 0; s < SCH; s++) {
        float2 du = sDU[s][ch];
        float2 bc = sBC[s][n];
        float dA  = __expf(du.x * A);
        h = fmaf(dA, h, du.y * bc.x);
        float p = row_reduce16(h * bc.y);
        if (n == 0) sY[s][ch] = p;
    }
    __syncthreads();
    for (int i = t; i < SCH * 16; i += 256) {
        int s = i >> 4, cc = i & 15;
        int lr = seq_to_lr(k, l0 + s);
        atomicAdd(&yp[(size_t)lr * DIN + d0 + cc], sY[s][cc]);
    }
}

// ---------------- kernel 5: gate + out-projection ---------------------------
constexpr int K5_PIX = 8;
__global__ __launch_bounds__(192) void k_out(
        const float* __restrict__ ysum, const float* __restrict__ zbuf,
        const float* __restrict__ W_out, float* __restrict__ out) {
    __shared__ float g[K5_PIX][DIN];       // 6 KB
    __shared__ float so[CDIM][K5_PIX];     // 3 KB
    int gp0 = blockIdx.x * K5_PIX;
    int b   = gp0 / LL;
    int l0  = gp0 - b * LL;
    int t   = threadIdx.x;
    for (int i = t; i < K5_PIX * DIN; i += 192) {
        int p = i / DIN, dd = i % DIN;
        size_t idx = (size_t)(gp0 + p) * DIN + dd;
        g[p][dd] = ysum[idx] * silu(zbuf[idx]);
    }
    __syncthreads();
    int f    = t % CDIM;        // output feature
    int half = t / CDIM;        // 0 or 1: which 4 pixels
    float acc[4] = {0.f, 0.f, 0.f, 0.f};
    for (int dd = 0; dd < DIN; dd++) {
        float wv = W_out[dd * CDIM + f];
#pragma unroll
        for (int p = 0; p < 4; p++)
            acc[p] = fmaf(g[half * 4 + p][dd], wv, acc[p]);
    }
#pragma unroll
    for (int p = 0; p < 4; p++) so[f][half * 4 + p] = acc[p];
    __syncthreads();
    for (int i = t; i < CDIM * K5_PIX; i += 192) {
        int f2 = i / K5_PIX, p2 = i % K5_PIX;
        out[((size_t)(b * CDIM + f2)) * LL + l0 + p2] = so[f2][p2];
    }
}

// ---------------- launch ----------------------------------------------------
extern "C" void kernel_launch(void* const* d_in, const int* in_sizes, int n_in,
                              void* d_out, int out_size, void* d_ws, size_t ws_size,
                              hipStream_t stream) {
    const float* x       = (const float*)d_in[0];
    const float* W_in    = (const float*)d_in[1];
    const float* W_conv  = (const float*)d_in[2];
    const float* b_conv  = (const float*)d_in[3];
    const float* W_xproj = (const float*)d_in[4];
    const float* W_dt    = (const float*)d_in[5];
    const float* b_dt    = (const float*)d_in[6];
    const float* A_logs  = (const float*)d_in[7];
    const float* Ds      = (const float*)d_in[8];
    const float* W_out   = (const float*)d_in[9];
    float* out = (float*)d_out;
    float* ws  = (float*)d_ws;

    float* xp    = ws + OFF_XP;      // dead after k_conv; reused as Pbuf
    float* z     = ws + OFF_Z;
    float* xi    = ws + OFF_XI;
    float* drbuf = ws + OFF_DR;
    float* Bbuf  = ws + OFF_B;
    float* Cbuf  = ws + OFF_C;
    float* ysum  = ws + OFF_Y;
    float* hend  = ws + OFF_HE;
    float* hin   = ws + OFF_HI;
    float* Wt    = ws + OFF_WT;
    float* Pbuf  = xp;

    k_wt<<<(NK * DIN * EPROJ + 255) / 256, 256, 0, stream>>>(W_xproj, Wt);
    k_inproj<<<(BATCH * LL) / K1_PIX, 384, 0, stream>>>(x, W_in, xp, z);
    k_conv<<<BATCH * LL, DIN, 0, stream>>>(xp, W_conv, b_conv, xi);
    dim3 g3((BATCH * LL) / K3_PIX, NK);
    k_xproj<<<g3, 256, 0, stream>>>(xi, Wt, Ds, drbuf, Bbuf, Cbuf, ysum);
    dim3 gs(NCH, NK * BATCH * CGRP);
    k_scanA<<<gs, 256, 0, stream>>>(xi, drbuf, Bbuf, A_logs, W_dt, b_dt, Pbuf, hend);
    k_scanB<<<(NK * BATCH * DIN * NST) / 256, 256, 0, stream>>>(Pbuf, hend, hin);
    k_scanC<<<gs, 256, 0, stream>>>(xi, drbuf, Bbuf, Cbuf, A_logs, W_dt, b_dt, hin, ysum);
    k_out<<<(BATCH * LL) / K5_PIX, 192, 0, stream>>>(ysum, z, W_out, out);
}

// Round 6
// 212.360 us; speedup vs baseline: 1.3084x; 1.3084x over previous
//
#include <hip/hip_runtime.h>
#include <math.h>

// ---------------- problem constants ----------------
constexpr int BATCH  = 2;
constexpr int CDIM   = 96;    // model dim
constexpr int HH     = 56;
constexpr int WW     = 56;
constexpr int LL     = HH * WW;          // 3136
constexpr int DIN    = 192;              // d_inner
constexpr int NK     = 4;                // directions
constexpr int NST    = 16;               // d_state
constexpr int RNK    = 6;                // dt_rank
constexpr int EPROJ  = RNK + 2 * NST;    // 38
constexpr int SCH    = 64;               // steps per scan chunk
constexpr int NCH    = LL / SCH;         // 49 chunks
constexpr int CGRP   = DIN / 16;         // 12 channel-groups of 16

// workspace layout (floats)
constexpr size_t SZ_PX   = (size_t)BATCH * LL * DIN;        // 1,204,224
constexpr size_t OFF_XP  = 0;                               // xp; reused as Pbuf
constexpr size_t OFF_Z   = OFF_XP + SZ_PX;
constexpr size_t OFF_XI  = OFF_Z  + SZ_PX;
constexpr size_t OFF_DR  = OFF_XI + SZ_PX;                  // dr: [kb][L][8]
constexpr size_t SZ_DR   = (size_t)NK * BATCH * LL * 8;
constexpr size_t OFF_B   = OFF_DR + SZ_DR;                  // B: K*B*L*16
constexpr size_t SZ_BC   = (size_t)NK * BATCH * LL * NST;
constexpr size_t OFF_C   = OFF_B + SZ_BC;
constexpr size_t OFF_Y   = OFF_C + SZ_BC;                   // ysum: B*L*192
constexpr size_t SZ_HS   = (size_t)NK * BATCH * NCH * DIN * NST;
constexpr size_t OFF_HE  = OFF_Y + SZ_PX;                   // h_end per chunk
constexpr size_t OFF_HI  = OFF_HE + SZ_HS;                  // h_in  per chunk
constexpr size_t OFF_WT  = OFF_HI + SZ_HS;                  // Wt: [k][e][d]
constexpr size_t SZ_WT   = (size_t)NK * EPROJ * DIN;        // 29,184

__device__ __forceinline__ float silu(float v) {
    return v / (1.0f + __expf(-v));
}

__device__ __forceinline__ float softplus_f(float x) {
    return (x > 20.0f) ? x : __logf(1.0f + __expf(x));
}

// full 16-lane-row sum via DPP row rotations (VALU only, no LDS pipe).
__device__ __forceinline__ float row_reduce16(float p) {
    p += __int_as_float(__builtin_amdgcn_update_dpp(0, __float_as_int(p), 0x128, 0xf, 0xf, true));
    p += __int_as_float(__builtin_amdgcn_update_dpp(0, __float_as_int(p), 0x124, 0xf, 0xf, true));
    p += __int_as_float(__builtin_amdgcn_update_dpp(0, __float_as_int(p), 0x122, 0xf, 0xf, true));
    p += __int_as_float(__builtin_amdgcn_update_dpp(0, __float_as_int(p), 0x121, 0xf, 0xf, true));
    return p;
}

// direction k, sequence position l -> row-major spatial index
__device__ __forceinline__ int seq_to_lr(int k, int l) {
    int q = l / WW;
    int r = l - q * WW;
    if (k == 0) return l;
    if (k == 1) return q * WW + (WW - 1 - r);
    if (k == 2) return r * WW + q;
    return (WW - 1 - r) * WW + q;
}

// direction k, row-major spatial index s -> sequence position (inverse map)
__device__ __forceinline__ int spatial_to_seq(int k, int s) {
    int h = s / WW;
    int w = s - h * WW;
    if (k == 0) return s;
    if (k == 1) return h * WW + (WW - 1 - w);
    if (k == 2) return w * WW + h;
    return w * WW + (WW - 1 - h);
}

// chunk-summary index: [c][kb][d][n]
__device__ __forceinline__ size_t hs_idx(int c, int kb, int d, int n) {
    return ((size_t)(c * (NK * BATCH) + kb) * DIN + d) * NST + n;
}

// ---------------- kernel 0: transpose W_xproj -> Wt[k][e][d] ----------------
__global__ __launch_bounds__(256) void k_wt(
        const float* __restrict__ W_xproj, float* __restrict__ Wt) {
    int i = blockIdx.x * 256 + threadIdx.x;
    if (i >= NK * DIN * EPROJ) return;
    int k = i / (DIN * EPROJ);
    int r = i % (DIN * EPROJ);
    int d = r / EPROJ;
    int e = r % EPROJ;
    Wt[((size_t)k * EPROJ + e) * DIN + d] = W_xproj[i];
}

// ---------------- kernel 1: in-projection (x^T @ W_in -> xp, z) --------------
constexpr int K1_PIX = 8;
__global__ __launch_bounds__(384) void k_inproj(
        const float* __restrict__ x, const float* __restrict__ W_in,
        float* __restrict__ xp, float* __restrict__ z) {
    __shared__ float sx[K1_PIX][100];   // padded to break bank conflicts
    int gp0 = blockIdx.x * K1_PIX;      // global pixel = b*LL + l
    int t   = threadIdx.x;
    int b   = gp0 / LL;
    int l0  = gp0 - b * LL;
    for (int i = t; i < K1_PIX * CDIM; i += 384) {
        int p = i % K1_PIX;
        int c = i / K1_PIX;
        sx[p][c] = x[((size_t)(b * CDIM + c)) * LL + l0 + p];
    }
    __syncthreads();
    int e = t;                          // 0..383 output feature
    float acc[K1_PIX];
#pragma unroll
    for (int p = 0; p < K1_PIX; p++) acc[p] = 0.0f;
    for (int c = 0; c < CDIM; c++) {
        float w = W_in[c * (2 * DIN) + e];
#pragma unroll
        for (int p = 0; p < K1_PIX; p++) acc[p] = fmaf(sx[p][c], w, acc[p]);
    }
    if (e < DIN) {
#pragma unroll
        for (int p = 0; p < K1_PIX; p++)
            xp[((size_t)(gp0 + p)) * DIN + e] = acc[p];
    } else {
        int e2 = e - DIN;
#pragma unroll
        for (int p = 0; p < K1_PIX; p++)
            z[((size_t)(gp0 + p)) * DIN + e2] = acc[p];
    }
}

// ---------------- kernel 2: depthwise conv 3x3 + bias + SiLU ----------------
__global__ __launch_bounds__(192) void k_conv(
        const float* __restrict__ xp, const float* __restrict__ Wc,
        const float* __restrict__ bc, float* __restrict__ xi) {
    int gp = blockIdx.x;
    int d  = threadIdx.x;
    int b  = gp / LL;
    int l  = gp - b * LL;
    int h  = l / WW;
    int w  = l - h * WW;
    float acc = bc[d];
#pragma unroll
    for (int dy = -1; dy <= 1; dy++) {
        int hh = h + dy;
        if (hh < 0 || hh >= HH) continue;
#pragma unroll
        for (int dx = -1; dx <= 1; dx++) {
            int ww = w + dx;
            if (ww < 0 || ww >= WW) continue;
            acc = fmaf(xp[((size_t)b * LL + hh * WW + ww) * DIN + d],
                       Wc[d * 9 + (dy + 1) * 3 + (dx + 1)], acc);
        }
    }
    xi[(size_t)gp * DIN + d] = silu(acc);
}

// ------- kernel 3: x-proj -> dr (rank-6), B, C; ysum = xi*sum_k(Ds) ----------
// Both operands staged in padded LDS (bank-conflict-free); thread (p0,eg)
// register-tiles 2 pixels x 3 e-values with float4 dots.
constexpr int K3_PIX = 32;
__global__ __launch_bounds__(256) void k_xproj(
        const float* __restrict__ xi, const float* __restrict__ Wt,
        const float* __restrict__ Ds,
        float* __restrict__ drbuf, float* __restrict__ Bbuf,
        float* __restrict__ Cbuf, float* __restrict__ ysum) {
    __shared__ float4 v4[K3_PIX][49];    // 25.1 KB, pad: bank=(4p+4j)%32
    __shared__ float4 sw4[EPROJ][49];    // 29.8 KB, pad: bank=(4e+4j)%32
    int k   = blockIdx.y;
    int gp0 = blockIdx.x * K3_PIX;
    int b   = gp0 / LL;
    int l0  = gp0 - b * LL;
    int t   = threadIdx.x;
    const float4* xin4 = (const float4*)(xi + (size_t)gp0 * DIN);
    for (int i = t; i < K3_PIX * 48; i += 256)
        v4[i / 48][i % 48] = xin4[i];
    const float4* wt4 = (const float4*)(Wt + (size_t)k * EPROJ * DIN);
    for (int i = t; i < EPROJ * 48; i += 256)
        sw4[i / 48][i % 48] = wt4[i];
    __syncthreads();
    if (k == 0) {
        const float* vf = (const float*)v4;
        for (int i = t; i < K3_PIX * DIN; i += 256) {
            int p = i / DIN, d = i % DIN;
            float dsum = Ds[d] + Ds[DIN + d] + Ds[2 * DIN + d] + Ds[3 * DIN + d];
            ysum[(size_t)gp0 * DIN + i] = vf[p * 196 + d] * dsum;
        }
    }
    int p0 = t & 15;            // pixel within 16-set
    int eg = t >> 4;            // e-group 0..15
    bool has3 = (eg < EPROJ - 32);      // eg < 6
    float acc[2][3] = {{0.f, 0.f, 0.f}, {0.f, 0.f, 0.f}};
    for (int j = 0; j < 48; j++) {
        float4 w0 = sw4[eg][j];
        float4 w1 = sw4[eg + 16][j];
        float4 w2 = has3 ? sw4[eg + 32][j] : make_float4(0.f, 0.f, 0.f, 0.f);
#pragma unroll
        for (int q = 0; q < 2; q++) {
            float4 vv = v4[p0 + 16 * q][j];
            acc[q][0] = fmaf(vv.x, w0.x, acc[q][0]); acc[q][0] = fmaf(vv.y, w0.y, acc[q][0]);
            acc[q][0] = fmaf(vv.z, w0.z, acc[q][0]); acc[q][0] = fmaf(vv.w, w0.w, acc[q][0]);
            acc[q][1] = fmaf(vv.x, w1.x, acc[q][1]); acc[q][1] = fmaf(vv.y, w1.y, acc[q][1]);
            acc[q][1] = fmaf(vv.z, w1.z, acc[q][1]); acc[q][1] = fmaf(vv.w, w1.w, acc[q][1]);
            acc[q][2] = fmaf(vv.x, w2.x, acc[q][2]); acc[q][2] = fmaf(vv.y, w2.y, acc[q][2]);
            acc[q][2] = fmaf(vv.z, w2.z, acc[q][2]); acc[q][2] = fmaf(vv.w, w2.w, acc[q][2]);
        }
    }
#pragma unroll
    for (int q = 0; q < 2; q++) {
        int p  = p0 + 16 * q;
        int ls = spatial_to_seq(k, l0 + p);
        size_t kb  = (size_t)(k * BATCH + b);
        size_t b8  = (kb * LL + ls) * 8;
        size_t b16 = (kb * LL + ls) * NST;
        // e0 = eg (0..15): dr if <6 else B
        if (eg < RNK) drbuf[b8 + eg] = acc[q][0];
        else          Bbuf[b16 + eg - RNK] = acc[q][0];
        // e1 = eg+16 (16..31): B if <22 else C
        int e1 = eg + 16;
        if (e1 < RNK + NST) Bbuf[b16 + e1 - RNK] = acc[q][1];
        else                Cbuf[b16 + e1 - RNK - NST] = acc[q][1];
        // e2 = eg+32 (32..37): C
        if (has3) Cbuf[b16 + eg + 32 - RNK - NST] = acc[q][2];
    }
}

// -------- kernel 4a: chunk-local scan -> per-chunk summary (P, h_end) --------
__global__ __launch_bounds__(256) void k_scanA(
        const float* __restrict__ xi, const float* __restrict__ drbuf,
        const float* __restrict__ Bbuf, const float* __restrict__ A_logs,
        const float* __restrict__ W_dt, const float* __restrict__ b_dt,
        float* __restrict__ Pbuf, float* __restrict__ hend) {
    __shared__ float2 sDU[SCH][16];   // {delta, delta*u}
    __shared__ float  sB1[SCH][16];
    int c   = blockIdx.x;
    int blk = blockIdx.y;
    int k   = blk / (BATCH * CGRP);
    int rem = blk % (BATCH * CGRP);
    int b   = rem / CGRP;
    int cg  = rem % CGRP;
    int d0  = cg * 16;
    int t    = threadIdx.x;
    int lane = t & 63, wave = t >> 6;
    int grp  = lane >> 4, n = lane & 15;
    int ch   = wave * 4 + grp;
    int d    = d0 + ch;
    float A = -__expf(A_logs[((size_t)(k * DIN + d)) * NST + n]);
    size_t kb = (size_t)(k * BATCH + b);
    const float* drp = drbuf + kb * LL * 8;
    const float* bp  = Bbuf  + kb * LL * NST;
    const float* up  = xi    + (size_t)b * LL * DIN;
    int dloc = d0 + (t & 15);
    float bb = b_dt[k * DIN + dloc];
    float w0 = W_dt[((size_t)k * RNK + 0) * DIN + dloc];
    float w1 = W_dt[((size_t)k * RNK + 1) * DIN + dloc];
    float w2 = W_dt[((size_t)k * RNK + 2) * DIN + dloc];
    float w3 = W_dt[((size_t)k * RNK + 3) * DIN + dloc];
    float w4 = W_dt[((size_t)k * RNK + 4) * DIN + dloc];
    float w5 = W_dt[((size_t)k * RNK + 5) * DIN + dloc];
    int l0 = c * SCH;
    for (int i = t; i < SCH * 16; i += 256) {
        int s = i >> 4, cc = i & 15;
        int l = l0 + s;
        int lr = seq_to_lr(k, l);
        float4 r03 = *(const float4*)(drp + (size_t)l * 8);
        float2 r45 = *(const float2*)(drp + (size_t)l * 8 + 4);
        float raw = bb;
        raw = fmaf(r03.x, w0, raw); raw = fmaf(r03.y, w1, raw);
        raw = fmaf(r03.z, w2, raw); raw = fmaf(r03.w, w3, raw);
        raw = fmaf(r45.x, w4, raw); raw = fmaf(r45.y, w5, raw);
        float dlt = softplus_f(raw);
        float u = up[(size_t)lr * DIN + d0 + cc];
        sDU[s][cc] = make_float2(dlt, dlt * u);
        sB1[s][cc] = bp[(size_t)l * NST + cc];
    }
    __syncthreads();
    float h = 0.0f, P = 1.0f;
#pragma unroll 8
    for (int s = 0; s < SCH; s++) {
        float2 du = sDU[s][ch];
        float dA  = __expf(du.x * A);
        h = fmaf(dA, h, du.y * sB1[s][n]);
        P *= dA;
    }
    size_t idx = hs_idx(c, (int)kb, d, n);
    Pbuf[idx] = P;
    hend[idx] = h;
}

// -------- kernel 4b: sequential combine over 49 chunk summaries --------------
__global__ __launch_bounds__(256) void k_scanB(
        const float* __restrict__ Pbuf, const float* __restrict__ hend,
        float* __restrict__ hin) {
    int tid = blockIdx.x * 256 + threadIdx.x;       // over K*B*DIN*NST = 24576
    int kb  = tid / (DIN * NST);
    int dn  = tid % (DIN * NST);
    float h = 0.0f;
    for (int c = 0; c < NCH; c++) {
        size_t idx = ((size_t)(c * (NK * BATCH) + kb)) * (DIN * NST) + dn;
        hin[idx] = h;
        h = fmaf(Pbuf[idx], h, hend[idx]);
    }
}

// -------- kernel 4c: chunk-local scan with true h_in; emit y -----------------
__global__ __launch_bounds__(256) void k_scanC(
        const float* __restrict__ xi, const float* __restrict__ drbuf,
        const float* __restrict__ Bbuf, const float* __restrict__ Cbuf,
        const float* __restrict__ A_logs, const float* __restrict__ W_dt,
        const float* __restrict__ b_dt, const float* __restrict__ hin,
        float* __restrict__ ysum) {
    __shared__ float2 sDU[SCH][16];   // {delta, delta*u}
    __shared__ float2 sBC[SCH][16];   // {B, C}
    __shared__ float  sY[SCH][16];
    int c   = blockIdx.x;
    int blk = blockIdx.y;
    int k   = blk / (BATCH * CGRP);
    int rem = blk % (BATCH * CGRP);
    int b   = rem / CGRP;
    int cg  = rem % CGRP;
    int d0  = cg * 16;
    int t    = threadIdx.x;
    int lane = t & 63, wave = t >> 6;
    int grp  = lane >> 4, n = lane & 15;
    int ch   = wave * 4 + grp;
    int d    = d0 + ch;
    float A = -__expf(A_logs[((size_t)(k * DIN + d)) * NST + n]);
    size_t kb = (size_t)(k * BATCH + b);
    const float* drp = drbuf + kb * LL * 8;
    const float* bp  = Bbuf  + kb * LL * NST;
    const float* cp  = Cbuf  + kb * LL * NST;
    const float* up  = xi    + (size_t)b * LL * DIN;
    float*       yp  = ysum  + (size_t)b * LL * DIN;
    int dloc = d0 + (t & 15);
    float bb = b_dt[k * DIN + dloc];
    float w0 = W_dt[((size_t)k * RNK + 0) * DIN + dloc];
    float w1 = W_dt[((size_t)k * RNK + 1) * DIN + dloc];
    float w2 = W_dt[((size_t)k * RNK + 2) * DIN + dloc];
    float w3 = W_dt[((size_t)k * RNK + 3) * DIN + dloc];
    float w4 = W_dt[((size_t)k * RNK + 4) * DIN + dloc];
    float w5 = W_dt[((size_t)k * RNK + 5) * DIN + dloc];
    int l0 = c * SCH;
    for (int i = t; i < SCH * 16; i += 256) {
        int s = i >> 4, cc = i & 15;
        int l = l0 + s;
        int lr = seq_to_lr(k, l);
        float4 r03 = *(const float4*)(drp + (size_t)l * 8);
        float2 r45 = *(const float2*)(drp + (size_t)l * 8 + 4);
        float raw = bb;
        raw = fmaf(r03.x, w0, raw); raw = fmaf(r03.y, w1, raw);
        raw = fmaf(r03.z, w2, raw); raw = fmaf(r03.w, w3, raw);
        raw = fmaf(r45.x, w4, raw); raw = fmaf(r45.y, w5, raw);
        float dlt = softplus_f(raw);
        float u = up[(size_t)lr * DIN + d0 + cc];
        sDU[s][cc] = make_float2(dlt, dlt * u);
        sBC[s][cc] = make_float2(bp[(size_t)l * NST + cc],
                                 cp[(size_t)l * NST + cc]);
    }
    float h = hin[hs_idx(c, (int)kb, d, n)];
    __syncthreads();
#pragma unroll 4
    for (int s = 0; s < SCH; s++) {
        float2 du = sDU[s][ch];
        float2 bc = sBC[s][n];
        float dA  = __expf(du.x * A);
        h = fmaf(dA, h, du.y * bc.x);
        float p = row_reduce16(h * bc.y);
        if (n == 0) sY[s][ch] = p;
    }
    __syncthreads();
    for (int i = t; i < SCH * 16; i += 256) {
        int s = i >> 4, cc = i & 15;
        int lr = seq_to_lr(k, l0 + s);
        atomicAdd(&yp[(size_t)lr * DIN + d0 + cc], sY[s][cc]);
    }
}

// ---------------- kernel 5: gate + out-projection ---------------------------
constexpr int K5_PIX = 8;
__global__ __launch_bounds__(192) void k_out(
        const float* __restrict__ ysum, const float* __restrict__ zbuf,
        const float* __restrict__ W_out, float* __restrict__ out) {
    __shared__ float g[K5_PIX][DIN];       // 6 KB
    __shared__ float so[CDIM][K5_PIX];     // 3 KB
    int gp0 = blockIdx.x * K5_PIX;
    int b   = gp0 / LL;
    int l0  = gp0 - b * LL;
    int t   = threadIdx.x;
    for (int i = t; i < K5_PIX * DIN; i += 192) {
        int p = i / DIN, dd = i % DIN;
        size_t idx = (size_t)(gp0 + p) * DIN + dd;
        g[p][dd] = ysum[idx] * silu(zbuf[idx]);
    }
    __syncthreads();
    int f    = t % CDIM;        // output feature
    int half = t / CDIM;        // 0 or 1: which 4 pixels
    float acc[4] = {0.f, 0.f, 0.f, 0.f};
    for (int dd = 0; dd < DIN; dd++) {
        float wv = W_out[dd * CDIM + f];
#pragma unroll
        for (int p = 0; p < 4; p++)
            acc[p] = fmaf(g[half * 4 + p][dd], wv, acc[p]);
    }
#pragma unroll
    for (int p = 0; p < 4; p++) so[f][half * 4 + p] = acc[p];
    __syncthreads();
    for (int i = t; i < CDIM * K5_PIX; i += 192) {
        int f2 = i / K5_PIX, p2 = i % K5_PIX;
        out[((size_t)(b * CDIM + f2)) * LL + l0 + p2] = so[f2][p2];
    }
}

// ---------------- launch ----------------------------------------------------
extern "C" void kernel_launch(void* const* d_in, const int* in_sizes, int n_in,
                              void* d_out, int out_size, void* d_ws, size_t ws_size,
                              hipStream_t stream) {
    const float* x       = (const float*)d_in[0];
    const float* W_in    = (const float*)d_in[1];
    const float* W_conv  = (const float*)d_in[2];
    const float* b_conv  = (const float*)d_in[3];
    const float* W_xproj = (const float*)d_in[4];
    const float* W_dt    = (const float*)d_in[5];
    const float* b_dt    = (const float*)d_in[6];
    const float* A_logs  = (const float*)d_in[7];
    const float* Ds      = (const float*)d_in[8];
    const float* W_out   = (const float*)d_in[9];
    float* out = (float*)d_out;
    float* ws  = (float*)d_ws;

    float* xp    = ws + OFF_XP;      // dead after k_conv; reused as Pbuf
    float* z     = ws + OFF_Z;
    float* xi    = ws + OFF_XI;
    float* drbuf = ws + OFF_DR;
    float* Bbuf  = ws + OFF_B;
    float* Cbuf  = ws + OFF_C;
    float* ysum  = ws + OFF_Y;
    float* hend  = ws + OFF_HE;
    float* hin   = ws + OFF_HI;
    float* Wt    = ws + OFF_WT;
    float* Pbuf  = xp;

    k_wt<<<(NK * DIN * EPROJ + 255) / 256, 256, 0, stream>>>(W_xproj, Wt);
    k_inproj<<<(BATCH * LL) / K1_PIX, 384, 0, stream>>>(x, W_in, xp, z);
    k_conv<<<BATCH * LL, DIN, 0, stream>>>(xp, W_conv, b_conv, xi);
    dim3 g3((BATCH * LL) / K3_PIX, NK);
    k_xproj<<<g3, 256, 0, stream>>>(xi, Wt, Ds, drbuf, Bbuf, Cbuf, ysum);
    dim3 gs(NCH, NK * BATCH * CGRP);
    k_scanA<<<gs, 256, 0, stream>>>(xi, drbuf, Bbuf, A_logs, W_dt, b_dt, Pbuf, hend);
    k_scanB<<<(NK * BATCH * DIN * NST) / 256, 256, 0, stream>>>(Pbuf, hend, hin);
    k_scanC<<<gs, 256, 0, stream>>>(xi, drbuf, Bbuf, Cbuf, A_logs, W_dt, b_dt, hin, ysum);
    k_out<<<(BATCH * LL) / K5_PIX, 192, 0, stream>>>(ysum, z, W_out, out);
}

// Round 7
// 209.531 us; speedup vs baseline: 1.3260x; 1.0135x over previous
//
#include <hip/hip_runtime.h>
#include <math.h>

// ---------------- problem constants ----------------
constexpr int BATCH  = 2;
constexpr int CDIM   = 96;    // model dim
constexpr int HH     = 56;
constexpr int WW     = 56;
constexpr int LL     = HH * WW;          // 3136
constexpr int DIN    = 192;              // d_inner
constexpr int NK     = 4;                // directions
constexpr int NST    = 16;               // d_state
constexpr int RNK    = 6;                // dt_rank
constexpr int EPROJ  = RNK + 2 * NST;    // 38
constexpr int SCH    = 64;               // steps per scan chunk
constexpr int NCH    = LL / SCH;         // 49 chunks
constexpr int CGRP   = DIN / 16;         // 12 channel-groups of 16

// workspace layout (floats)
constexpr size_t SZ_PX   = (size_t)BATCH * LL * DIN;        // 1,204,224
constexpr size_t OFF_XP  = 0;                               // xp; reused as Pbuf
constexpr size_t OFF_Z   = OFF_XP + SZ_PX;
constexpr size_t OFF_XI  = OFF_Z  + SZ_PX;
constexpr size_t OFF_DR  = OFF_XI + SZ_PX;                  // dr: [kb][L][8]
constexpr size_t SZ_DR   = (size_t)NK * BATCH * LL * 8;
constexpr size_t OFF_B   = OFF_DR + SZ_DR;                  // B: K*B*L*16
constexpr size_t SZ_BC   = (size_t)NK * BATCH * LL * NST;
constexpr size_t OFF_C   = OFF_B + SZ_BC;
constexpr size_t OFF_Y   = OFF_C + SZ_BC;                   // ysum: B*L*192
constexpr size_t SZ_HS   = (size_t)NK * BATCH * NCH * DIN * NST;
constexpr size_t OFF_HE  = OFF_Y + SZ_PX;                   // h_end per chunk
constexpr size_t OFF_HI  = OFF_HE + SZ_HS;                  // h_in  per chunk
constexpr size_t OFF_WT  = OFF_HI + SZ_HS;                  // Wt: [k][e][d]
constexpr size_t SZ_WT   = (size_t)NK * EPROJ * DIN;        // 29,184

__device__ __forceinline__ float silu(float v) {
    return v / (1.0f + __expf(-v));
}

__device__ __forceinline__ float softplus_f(float x) {
    return (x > 20.0f) ? x : __logf(1.0f + __expf(x));
}

// full 16-lane-row sum via DPP row rotations (VALU only, no LDS pipe).
__device__ __forceinline__ float row_reduce16(float p) {
    p += __int_as_float(__builtin_amdgcn_update_dpp(0, __float_as_int(p), 0x128, 0xf, 0xf, true));
    p += __int_as_float(__builtin_amdgcn_update_dpp(0, __float_as_int(p), 0x124, 0xf, 0xf, true));
    p += __int_as_float(__builtin_amdgcn_update_dpp(0, __float_as_int(p), 0x122, 0xf, 0xf, true));
    p += __int_as_float(__builtin_amdgcn_update_dpp(0, __float_as_int(p), 0x121, 0xf, 0xf, true));
    return p;
}

// direction k, sequence position l -> row-major spatial index
__device__ __forceinline__ int seq_to_lr(int k, int l) {
    int q = l / WW;
    int r = l - q * WW;
    if (k == 0) return l;
    if (k == 1) return q * WW + (WW - 1 - r);
    if (k == 2) return r * WW + q;
    return (WW - 1 - r) * WW + q;
}

// direction k, row-major spatial index s -> sequence position (inverse map)
__device__ __forceinline__ int spatial_to_seq(int k, int s) {
    int h = s / WW;
    int w = s - h * WW;
    if (k == 0) return s;
    if (k == 1) return h * WW + (WW - 1 - w);
    if (k == 2) return w * WW + h;
    return w * WW + (WW - 1 - h);
}

// chunk-summary index: [c][kb][d][n]
__device__ __forceinline__ size_t hs_idx(int c, int kb, int d, int n) {
    return ((size_t)(c * (NK * BATCH) + kb) * DIN + d) * NST + n;
}

// ---------------- kernel 0: transpose W_xproj -> Wt[k][e][d] ----------------
__global__ __launch_bounds__(256) void k_wt(
        const float* __restrict__ W_xproj, float* __restrict__ Wt) {
    int i = blockIdx.x * 256 + threadIdx.x;
    if (i >= NK * DIN * EPROJ) return;
    int k = i / (DIN * EPROJ);
    int r = i % (DIN * EPROJ);
    int d = r / EPROJ;
    int e = r % EPROJ;
    Wt[((size_t)k * EPROJ + e) * DIN + d] = W_xproj[i];
}

// ---------------- kernel 1: in-projection (x^T @ W_in -> xp, z) --------------
// x-tile transposed in LDS: compute phase does 2 broadcast b128 reads per c.
constexpr int K1_PIX = 8;
__global__ __launch_bounds__(384) void k_inproj(
        const float* __restrict__ x, const float* __restrict__ W_in,
        float* __restrict__ xp, float* __restrict__ z) {
    __shared__ float sxT[CDIM][K1_PIX];   // [c][p], 3 KB
    int gp0 = blockIdx.x * K1_PIX;      // global pixel = b*LL + l
    int t   = threadIdx.x;
    int b   = gp0 / LL;
    int l0  = gp0 - b * LL;
    for (int i = t; i < CDIM * K1_PIX; i += 384) {
        int c = i >> 3, p = i & 7;
        sxT[c][p] = x[((size_t)(b * CDIM + c)) * LL + l0 + p];
    }
    __syncthreads();
    int e = t;                          // 0..383 output feature
    float acc[K1_PIX];
#pragma unroll
    for (int p = 0; p < K1_PIX; p++) acc[p] = 0.0f;
    const float4* sx4 = (const float4*)sxT;
#pragma unroll 4
    for (int c = 0; c < CDIM; c++) {
        float w  = W_in[c * (2 * DIN) + e];
        float4 va = sx4[2 * c];
        float4 vb = sx4[2 * c + 1];
        acc[0] = fmaf(va.x, w, acc[0]); acc[1] = fmaf(va.y, w, acc[1]);
        acc[2] = fmaf(va.z, w, acc[2]); acc[3] = fmaf(va.w, w, acc[3]);
        acc[4] = fmaf(vb.x, w, acc[4]); acc[5] = fmaf(vb.y, w, acc[5]);
        acc[6] = fmaf(vb.z, w, acc[6]); acc[7] = fmaf(vb.w, w, acc[7]);
    }
    if (e < DIN) {
#pragma unroll
        for (int p = 0; p < K1_PIX; p++)
            xp[((size_t)(gp0 + p)) * DIN + e] = acc[p];
    } else {
        int e2 = e - DIN;
#pragma unroll
        for (int p = 0; p < K1_PIX; p++)
            z[((size_t)(gp0 + p)) * DIN + e2] = acc[p];
    }
}

// ---------------- kernel 2: depthwise conv 3x3 + bias + SiLU ----------------
__global__ __launch_bounds__(192) void k_conv(
        const float* __restrict__ xp, const float* __restrict__ Wc,
        const float* __restrict__ bc, float* __restrict__ xi) {
    int gp = blockIdx.x;
    int d  = threadIdx.x;
    int b  = gp / LL;
    int l  = gp - b * LL;
    int h  = l / WW;
    int w  = l - h * WW;
    float acc = bc[d];
#pragma unroll
    for (int dy = -1; dy <= 1; dy++) {
        int hh = h + dy;
        if (hh < 0 || hh >= HH) continue;
#pragma unroll
        for (int dx = -1; dx <= 1; dx++) {
            int ww = w + dx;
            if (ww < 0 || ww >= WW) continue;
            acc = fmaf(xp[((size_t)b * LL + hh * WW + ww) * DIN + d],
                       Wc[d * 9 + (dy + 1) * 3 + (dx + 1)], acc);
        }
    }
    xi[(size_t)gp * DIN + d] = silu(acc);
}

// ------- kernel 3: x-proj -> dr (rank-6), B, C; ysum = xi*sum_k(Ds) ----------
constexpr int K3_PIX = 32;
__global__ __launch_bounds__(256) void k_xproj(
        const float* __restrict__ xi, const float* __restrict__ Wt,
        const float* __restrict__ Ds,
        float* __restrict__ drbuf, float* __restrict__ Bbuf,
        float* __restrict__ Cbuf, float* __restrict__ ysum) {
    __shared__ float4 v4[K3_PIX][49];    // 25.1 KB, pad: bank=(4p+4j)%32
    __shared__ float4 sw4[EPROJ][49];    // 29.8 KB, pad: bank=(4e+4j)%32
    int k   = blockIdx.y;
    int gp0 = blockIdx.x * K3_PIX;
    int b   = gp0 / LL;
    int l0  = gp0 - b * LL;
    int t   = threadIdx.x;
    const float4* xin4 = (const float4*)(xi + (size_t)gp0 * DIN);
    for (int i = t; i < K3_PIX * 48; i += 256)
        v4[i / 48][i % 48] = xin4[i];
    const float4* wt4 = (const float4*)(Wt + (size_t)k * EPROJ * DIN);
    for (int i = t; i < EPROJ * 48; i += 256)
        sw4[i / 48][i % 48] = wt4[i];
    __syncthreads();
    if (k == 0) {
        const float* vf = (const float*)v4;
        for (int i = t; i < K3_PIX * DIN; i += 256) {
            int p = i / DIN, d = i % DIN;
            float dsum = Ds[d] + Ds[DIN + d] + Ds[2 * DIN + d] + Ds[3 * DIN + d];
            ysum[(size_t)gp0 * DIN + i] = vf[p * 196 + d] * dsum;
        }
    }
    int p0 = t & 15;            // pixel within 16-set
    int eg = t >> 4;            // e-group 0..15
    bool has3 = (eg < EPROJ - 32);      // eg < 6
    float acc[2][3] = {{0.f, 0.f, 0.f}, {0.f, 0.f, 0.f}};
    for (int j = 0; j < 48; j++) {
        float4 w0 = sw4[eg][j];
        float4 w1 = sw4[eg + 16][j];
        float4 w2 = has3 ? sw4[eg + 32][j] : make_float4(0.f, 0.f, 0.f, 0.f);
#pragma unroll
        for (int q = 0; q < 2; q++) {
            float4 vv = v4[p0 + 16 * q][j];
            acc[q][0] = fmaf(vv.x, w0.x, acc[q][0]); acc[q][0] = fmaf(vv.y, w0.y, acc[q][0]);
            acc[q][0] = fmaf(vv.z, w0.z, acc[q][0]); acc[q][0] = fmaf(vv.w, w0.w, acc[q][0]);
            acc[q][1] = fmaf(vv.x, w1.x, acc[q][1]); acc[q][1] = fmaf(vv.y, w1.y, acc[q][1]);
            acc[q][1] = fmaf(vv.z, w1.z, acc[q][1]); acc[q][1] = fmaf(vv.w, w1.w, acc[q][1]);
            acc[q][2] = fmaf(vv.x, w2.x, acc[q][2]); acc[q][2] = fmaf(vv.y, w2.y, acc[q][2]);
            acc[q][2] = fmaf(vv.z, w2.z, acc[q][2]); acc[q][2] = fmaf(vv.w, w2.w, acc[q][2]);
        }
    }
#pragma unroll
    for (int q = 0; q < 2; q++) {
        int p  = p0 + 16 * q;
        int ls = spatial_to_seq(k, l0 + p);
        size_t kb  = (size_t)(k * BATCH + b);
        size_t b8  = (kb * LL + ls) * 8;
        size_t b16 = (kb * LL + ls) * NST;
        if (eg < RNK) drbuf[b8 + eg] = acc[q][0];
        else          Bbuf[b16 + eg - RNK] = acc[q][0];
        int e1 = eg + 16;
        if (e1 < RNK + NST) Bbuf[b16 + e1 - RNK] = acc[q][1];
        else                Cbuf[b16 + e1 - RNK - NST] = acc[q][1];
        if (has3) Cbuf[b16 + eg + 32 - RNK - NST] = acc[q][2];
    }
}

// -------- kernel 4a: chunk-local scan -> per-chunk summary (P, h_end) --------
// Time-major LDS: hot loop reads 4 steps per b128.
__global__ __launch_bounds__(256) void k_scanA(
        const float* __restrict__ xi, const float* __restrict__ drbuf,
        const float* __restrict__ Bbuf, const float* __restrict__ A_logs,
        const float* __restrict__ W_dt, const float* __restrict__ b_dt,
        float* __restrict__ Pbuf, float* __restrict__ hend) {
    __shared__ float2 sDU2[16][SCH + 2];   // [ch][s] {delta, delta*u}, 8.25 KB
    __shared__ float  sB1t[16][SCH + 4];   // [n][s], 4.25 KB
    int c   = blockIdx.x;
    int blk = blockIdx.y;
    int k   = blk / (BATCH * CGRP);
    int rem = blk % (BATCH * CGRP);
    int b   = rem / CGRP;
    int cg  = rem % CGRP;
    int d0  = cg * 16;
    int t    = threadIdx.x;
    int lane = t & 63, wave = t >> 6;
    int grp  = lane >> 4, n = lane & 15;
    int ch   = wave * 4 + grp;
    int d    = d0 + ch;
    float A = -__expf(A_logs[((size_t)(k * DIN + d)) * NST + n]);
    size_t kb = (size_t)(k * BATCH + b);
    const float* drp = drbuf + kb * LL * 8;
    const float* bp  = Bbuf  + kb * LL * NST;
    const float* up  = xi    + (size_t)b * LL * DIN;
    int dloc = d0 + (t & 15);
    float bb = b_dt[k * DIN + dloc];
    float w0 = W_dt[((size_t)k * RNK + 0) * DIN + dloc];
    float w1 = W_dt[((size_t)k * RNK + 1) * DIN + dloc];
    float w2 = W_dt[((size_t)k * RNK + 2) * DIN + dloc];
    float w3 = W_dt[((size_t)k * RNK + 3) * DIN + dloc];
    float w4 = W_dt[((size_t)k * RNK + 4) * DIN + dloc];
    float w5 = W_dt[((size_t)k * RNK + 5) * DIN + dloc];
    int l0 = c * SCH;
    for (int i = t; i < SCH * 16; i += 256) {
        int s = i >> 4, cc = i & 15;
        int l = l0 + s;
        int lr = seq_to_lr(k, l);
        float4 r03 = *(const float4*)(drp + (size_t)l * 8);
        float2 r45 = *(const float2*)(drp + (size_t)l * 8 + 4);
        float raw = bb;
        raw = fmaf(r03.x, w0, raw); raw = fmaf(r03.y, w1, raw);
        raw = fmaf(r03.z, w2, raw); raw = fmaf(r03.w, w3, raw);
        raw = fmaf(r45.x, w4, raw); raw = fmaf(r45.y, w5, raw);
        float dlt = softplus_f(raw);
        float u = up[(size_t)lr * DIN + d0 + cc];
        sDU2[cc][s] = make_float2(dlt, dlt * u);
        sB1t[cc][s] = bp[(size_t)l * NST + cc];
    }
    __syncthreads();
    float h = 0.0f, P = 1.0f;
#pragma unroll 2
    for (int s4 = 0; s4 < SCH; s4 += 4) {
        float4 duA = *(const float4*)&sDU2[ch][s4];
        float4 duB = *(const float4*)&sDU2[ch][s4 + 2];
        float4 bq  = *(const float4*)&sB1t[n][s4];
        float dA;
        dA = __expf(duA.x * A); h = fmaf(dA, h, duA.y * bq.x); P *= dA;
        dA = __expf(duA.z * A); h = fmaf(dA, h, duA.w * bq.y); P *= dA;
        dA = __expf(duB.x * A); h = fmaf(dA, h, duB.y * bq.z); P *= dA;
        dA = __expf(duB.z * A); h = fmaf(dA, h, duB.w * bq.w); P *= dA;
    }
    size_t idx = hs_idx(c, (int)kb, d, n);
    Pbuf[idx] = P;
    hend[idx] = h;
}

// -------- kernel 4b: sequential combine over 49 chunk summaries --------------
__global__ __launch_bounds__(256) void k_scanB(
        const float* __restrict__ Pbuf, const float* __restrict__ hend,
        float* __restrict__ hin) {
    int tid = blockIdx.x * 256 + threadIdx.x;       // over K*B*DIN*NST = 24576
    int kb  = tid / (DIN * NST);
    int dn  = tid % (DIN * NST);
    float h = 0.0f;
    for (int c = 0; c < NCH; c++) {
        size_t idx = ((size_t)(c * (NK * BATCH) + kb)) * (DIN * NST) + dn;
        hin[idx] = h;
        h = fmaf(Pbuf[idx], h, hend[idx]);
    }
}

// -------- kernel 4c: chunk-local scan with true h_in; emit y -----------------
__global__ __launch_bounds__(256) void k_scanC(
        const float* __restrict__ xi, const float* __restrict__ drbuf,
        const float* __restrict__ Bbuf, const float* __restrict__ Cbuf,
        const float* __restrict__ A_logs, const float* __restrict__ W_dt,
        const float* __restrict__ b_dt, const float* __restrict__ hin,
        float* __restrict__ ysum) {
    __shared__ float2 sDU2[16][SCH + 2];   // [ch][s] {delta, delta*u}
    __shared__ float2 sBC2[16][SCH + 2];   // [n][s]  {B, C}
    __shared__ float  sY[16][SCH + 4];     // [ch][s]
    int c   = blockIdx.x;
    int blk = blockIdx.y;
    int k   = blk / (BATCH * CGRP);
    int rem = blk % (BATCH * CGRP);
    int b   = rem / CGRP;
    int cg  = rem % CGRP;
    int d0  = cg * 16;
    int t    = threadIdx.x;
    int lane = t & 63, wave = t >> 6;
    int grp  = lane >> 4, n = lane & 15;
    int ch   = wave * 4 + grp;
    int d    = d0 + ch;
    float A = -__expf(A_logs[((size_t)(k * DIN + d)) * NST + n]);
    size_t kb = (size_t)(k * BATCH + b);
    const float* drp = drbuf + kb * LL * 8;
    const float* bp  = Bbuf  + kb * LL * NST;
    const float* cp  = Cbuf  + kb * LL * NST;
    const float* up  = xi    + (size_t)b * LL * DIN;
    float*       yp  = ysum  + (size_t)b * LL * DIN;
    int dloc = d0 + (t & 15);
    float bb = b_dt[k * DIN + dloc];
    float w0 = W_dt[((size_t)k * RNK + 0) * DIN + dloc];
    float w1 = W_dt[((size_t)k * RNK + 1) * DIN + dloc];
    float w2 = W_dt[((size_t)k * RNK + 2) * DIN + dloc];
    float w3 = W_dt[((size_t)k * RNK + 3) * DIN + dloc];
    float w4 = W_dt[((size_t)k * RNK + 4) * DIN + dloc];
    float w5 = W_dt[((size_t)k * RNK + 5) * DIN + dloc];
    int l0 = c * SCH;
    for (int i = t; i < SCH * 16; i += 256) {
        int s = i >> 4, cc = i & 15;
        int l = l0 + s;
        int lr = seq_to_lr(k, l);
        float4 r03 = *(const float4*)(drp + (size_t)l * 8);
        float2 r45 = *(const float2*)(drp + (size_t)l * 8 + 4);
        float raw = bb;
        raw = fmaf(r03.x, w0, raw); raw = fmaf(r03.y, w1, raw);
        raw = fmaf(r03.z, w2, raw); raw = fmaf(r03.w, w3, raw);
        raw = fmaf(r45.x, w4, raw); raw = fmaf(r45.y, w5, raw);
        float dlt = softplus_f(raw);
        float u = up[(size_t)lr * DIN + d0 + cc];
        sDU2[cc][s] = make_float2(dlt, dlt * u);
        sBC2[cc][s] = make_float2(bp[(size_t)l * NST + cc],
                                  cp[(size_t)l * NST + cc]);
    }
    float h = hin[hs_idx(c, (int)kb, d, n)];
    __syncthreads();
#pragma unroll 2
    for (int s4 = 0; s4 < SCH; s4 += 4) {
        float4 duA = *(const float4*)&sDU2[ch][s4];
        float4 duB = *(const float4*)&sDU2[ch][s4 + 2];
        float4 bcA = *(const float4*)&sBC2[n][s4];
        float4 bcB = *(const float4*)&sBC2[n][s4 + 2];
        float dA, y0, y1, y2, y3;
        dA = __expf(duA.x * A); h = fmaf(dA, h, duA.y * bcA.x); y0 = row_reduce16(h * bcA.y);
        dA = __expf(duA.z * A); h = fmaf(dA, h, duA.w * bcA.z); y1 = row_reduce16(h * bcA.w);
        dA = __expf(duB.x * A); h = fmaf(dA, h, duB.y * bcB.x); y2 = row_reduce16(h * bcB.y);
        dA = __expf(duB.z * A); h = fmaf(dA, h, duB.w * bcB.z); y3 = row_reduce16(h * bcB.w);
        if (n == 0) *(float4*)&sY[ch][s4] = make_float4(y0, y1, y2, y3);
    }
    __syncthreads();
    for (int i = t; i < SCH * 16; i += 256) {
        int s = i >> 4, cc = i & 15;
        int lr = seq_to_lr(k, l0 + s);
        atomicAdd(&yp[(size_t)lr * DIN + d0 + cc], sY[cc][s]);
    }
}

// ---------------- kernel 5: gate + out-projection ---------------------------
constexpr int K5_PIX = 8;
__global__ __launch_bounds__(192) void k_out(
        const float* __restrict__ ysum, const float* __restrict__ zbuf,
        const float* __restrict__ W_out, float* __restrict__ out) {
    __shared__ float g[DIN][12];           // [dd][p] padded: aligned b128 reads
    __shared__ float so[CDIM][9];          // padded stores
    int gp0 = blockIdx.x * K5_PIX;
    int b   = gp0 / LL;
    int l0  = gp0 - b * LL;
    int t   = threadIdx.x;
    for (int i = t; i < K5_PIX * DIN; i += 192) {
        int p = i / DIN, dd = i % DIN;
        size_t idx = (size_t)(gp0 + p) * DIN + dd;
        g[dd][p] = ysum[idx] * silu(zbuf[idx]);
    }
    __syncthreads();
    int f    = t % CDIM;        // output feature
    int half = t / CDIM;        // 0 or 1: which 4 pixels
    float acc[4] = {0.f, 0.f, 0.f, 0.f};
#pragma unroll 4
    for (int dd = 0; dd < DIN; dd++) {
        float wv = W_out[dd * CDIM + f];
        float4 gv = *(const float4*)&g[dd][half * 4];
        acc[0] = fmaf(gv.x, wv, acc[0]);
        acc[1] = fmaf(gv.y, wv, acc[1]);
        acc[2] = fmaf(gv.z, wv, acc[2]);
        acc[3] = fmaf(gv.w, wv, acc[3]);
    }
#pragma unroll
    for (int p = 0; p < 4; p++) so[f][half * 4 + p] = acc[p];
    __syncthreads();
    for (int i = t; i < CDIM * K5_PIX; i += 192) {
        int f2 = i / K5_PIX, p2 = i % K5_PIX;
        out[((size_t)(b * CDIM + f2)) * LL + l0 + p2] = so[f2][p2];
    }
}

// ---------------- launch ----------------------------------------------------
extern "C" void kernel_launch(void* const* d_in, const int* in_sizes, int n_in,
                              void* d_out, int out_size, void* d_ws, size_t ws_size,
                              hipStream_t stream) {
    const float* x       = (const float*)d_in[0];
    const float* W_in    = (const float*)d_in[1];
    const float* W_conv  = (const float*)d_in[2];
    const float* b_conv  = (const float*)d_in[3];
    const float* W_xproj = (const float*)d_in[4];
    const float* W_dt    = (const float*)d_in[5];
    const float* b_dt    = (const float*)d_in[6];
    const float* A_logs  = (const float*)d_in[7];
    const float* Ds      = (const float*)d_in[8];
    const float* W_out   = (const float*)d_in[9];
    float* out = (float*)d_out;
    float* ws  = (float*)d_ws;

    float* xp    = ws + OFF_XP;      // dead after k_conv; reused as Pbuf
    float* z     = ws + OFF_Z;
    float* xi    = ws + OFF_XI;
    float* drbuf = ws + OFF_DR;
    float* Bbuf  = ws + OFF_B;
    float* Cbuf  = ws + OFF_C;
    float* ysum  = ws + OFF_Y;
    float* hend  = ws + OFF_HE;
    float* hin   = ws + OFF_HI;
    float* Wt    = ws + OFF_WT;
    float* Pbuf  = xp;

    k_wt<<<(NK * DIN * EPROJ + 255) / 256, 256, 0, stream>>>(W_xproj, Wt);
    k_inproj<<<(BATCH * LL) / K1_PIX, 384, 0, stream>>>(x, W_in, xp, z);
    k_conv<<<BATCH * LL, DIN, 0, stream>>>(xp, W_conv, b_conv, xi);
    dim3 g3((BATCH * LL) / K3_PIX, NK);
    k_xproj<<<g3, 256, 0, stream>>>(xi, Wt, Ds, drbuf, Bbuf, Cbuf, ysum);
    dim3 gs(NCH, NK * BATCH * CGRP);
    k_scanA<<<gs, 256, 0, stream>>>(xi, drbuf, Bbuf, A_logs, W_dt, b_dt, Pbuf, hend);
    k_scanB<<<(NK * BATCH * DIN * NST) / 256, 256, 0, stream>>>(Pbuf, hend, hin);
    k_scanC<<<gs, 256, 0, stream>>>(xi, drbuf, Bbuf, Cbuf, A_logs, W_dt, b_dt, hin, ysum);
    k_out<<<(BATCH * LL) / K5_PIX, 192, 0, stream>>>(ysum, z, W_out, out);
}

// Round 8
// 208.647 us; speedup vs baseline: 1.3317x; 1.0042x over previous
//
#include <hip/hip_runtime.h>
#include <math.h>

// ---------------- problem constants ----------------
constexpr int BATCH  = 2;
constexpr int CDIM   = 96;    // model dim
constexpr int HH     = 56;
constexpr int WW     = 56;
constexpr int LL     = HH * WW;          // 3136
constexpr int DIN    = 192;              // d_inner
constexpr int NK     = 4;                // directions
constexpr int NST    = 16;               // d_state
constexpr int RNK    = 6;                // dt_rank
constexpr int EPROJ  = RNK + 2 * NST;    // 38
constexpr int SCH    = 64;               // steps per scan chunk
constexpr int NCH    = LL / SCH;         // 49 chunks
constexpr int CGRP   = DIN / 16;         // 12 channel-groups of 16

// workspace layout (floats)
constexpr size_t SZ_PX   = (size_t)BATCH * LL * DIN;        // 1,204,224
constexpr size_t OFF_XP  = 0;                               // xp; reused as Pbuf
constexpr size_t OFF_Z   = OFF_XP + SZ_PX;
constexpr size_t OFF_XI  = OFF_Z  + SZ_PX;
constexpr size_t OFF_DR  = OFF_XI + SZ_PX;                  // dr: [kb][L][8]
constexpr size_t SZ_DR   = (size_t)NK * BATCH * LL * 8;
constexpr size_t OFF_B   = OFF_DR + SZ_DR;                  // B: K*B*L*16
constexpr size_t SZ_BC   = (size_t)NK * BATCH * LL * NST;
constexpr size_t OFF_C   = OFF_B + SZ_BC;
constexpr size_t OFF_YD  = OFF_C + SZ_BC;                   // ydir: [k][b][sp][d]
constexpr size_t SZ_YD   = (size_t)NK * BATCH * LL * DIN;   // 4,816,896
constexpr size_t OFF_HE  = OFF_YD + SZ_YD;                  // h_end per chunk
constexpr size_t SZ_HS   = (size_t)NK * BATCH * NCH * DIN * NST;
constexpr size_t OFF_HI  = OFF_HE + SZ_HS;                  // h_in  per chunk
constexpr size_t OFF_WT  = OFF_HI + SZ_HS;                  // Wt: [k][e][d]
constexpr size_t SZ_WT   = (size_t)NK * EPROJ * DIN;        // 29,184

__device__ __forceinline__ float silu(float v) {
    return v / (1.0f + __expf(-v));
}

__device__ __forceinline__ float softplus_f(float x) {
    return (x > 20.0f) ? x : __logf(1.0f + __expf(x));
}

// full 16-lane-row sum via DPP row rotations (VALU only, no LDS pipe).
__device__ __forceinline__ float row_reduce16(float p) {
    p += __int_as_float(__builtin_amdgcn_update_dpp(0, __float_as_int(p), 0x128, 0xf, 0xf, true));
    p += __int_as_float(__builtin_amdgcn_update_dpp(0, __float_as_int(p), 0x124, 0xf, 0xf, true));
    p += __int_as_float(__builtin_amdgcn_update_dpp(0, __float_as_int(p), 0x122, 0xf, 0xf, true));
    p += __int_as_float(__builtin_amdgcn_update_dpp(0, __float_as_int(p), 0x121, 0xf, 0xf, true));
    return p;
}

// direction k, sequence position l -> row-major spatial index
__device__ __forceinline__ int seq_to_lr(int k, int l) {
    int q = l / WW;
    int r = l - q * WW;
    if (k == 0) return l;
    if (k == 1) return q * WW + (WW - 1 - r);
    if (k == 2) return r * WW + q;
    return (WW - 1 - r) * WW + q;
}

// direction k, row-major spatial index s -> sequence position (inverse map)
__device__ __forceinline__ int spatial_to_seq(int k, int s) {
    int h = s / WW;
    int w = s - h * WW;
    if (k == 0) return s;
    if (k == 1) return h * WW + (WW - 1 - w);
    if (k == 2) return w * WW + h;
    return w * WW + (WW - 1 - h);
}

// chunk-summary index: [c][kb][d][n]
__device__ __forceinline__ size_t hs_idx(int c, int kb, int d, int n) {
    return ((size_t)(c * (NK * BATCH) + kb) * DIN + d) * NST + n;
}

// ---------------- kernel 1: in-projection (x^T @ W_in -> xp, z) --------------
// Side job: first threads also transpose W_xproj -> Wt[k][e][d] (replaces k_wt).
constexpr int K1_PIX = 8;
__global__ __launch_bounds__(384) void k_inproj(
        const float* __restrict__ x, const float* __restrict__ W_in,
        const float* __restrict__ W_xproj,
        float* __restrict__ xp, float* __restrict__ z, float* __restrict__ Wt) {
    __shared__ float sxT[CDIM][K1_PIX];   // [c][p], 3 KB
    int gp0 = blockIdx.x * K1_PIX;      // global pixel = b*LL + l
    int t   = threadIdx.x;
    int b   = gp0 / LL;
    int l0  = gp0 - b * LL;
    // side job: Wt transpose (independent of this block's main work)
    int gid = blockIdx.x * 384 + t;
    if (gid < NK * DIN * EPROJ) {
        int k = gid / (DIN * EPROJ);
        int r = gid % (DIN * EPROJ);
        int d = r / EPROJ;
        int e = r % EPROJ;
        Wt[((size_t)k * EPROJ + e) * DIN + d] = W_xproj[gid];
    }
    for (int i = t; i < CDIM * K1_PIX; i += 384) {
        int c = i >> 3, p = i & 7;
        sxT[c][p] = x[((size_t)(b * CDIM + c)) * LL + l0 + p];
    }
    __syncthreads();
    int e = t;                          // 0..383 output feature
    float acc[K1_PIX];
#pragma unroll
    for (int p = 0; p < K1_PIX; p++) acc[p] = 0.0f;
    const float4* sx4 = (const float4*)sxT;
#pragma unroll 4
    for (int c = 0; c < CDIM; c++) {
        float w  = W_in[c * (2 * DIN) + e];
        float4 va = sx4[2 * c];
        float4 vb = sx4[2 * c + 1];
        acc[0] = fmaf(va.x, w, acc[0]); acc[1] = fmaf(va.y, w, acc[1]);
        acc[2] = fmaf(va.z, w, acc[2]); acc[3] = fmaf(va.w, w, acc[3]);
        acc[4] = fmaf(vb.x, w, acc[4]); acc[5] = fmaf(vb.y, w, acc[5]);
        acc[6] = fmaf(vb.z, w, acc[6]); acc[7] = fmaf(vb.w, w, acc[7]);
    }
    if (e < DIN) {
#pragma unroll
        for (int p = 0; p < K1_PIX; p++)
            xp[((size_t)(gp0 + p)) * DIN + e] = acc[p];
    } else {
        int e2 = e - DIN;
#pragma unroll
        for (int p = 0; p < K1_PIX; p++)
            z[((size_t)(gp0 + p)) * DIN + e2] = acc[p];
    }
}

// ---------------- kernel 2: depthwise conv 3x3 + bias + SiLU ----------------
__global__ __launch_bounds__(192) void k_conv(
        const float* __restrict__ xp, const float* __restrict__ Wc,
        const float* __restrict__ bc, float* __restrict__ xi) {
    int gp = blockIdx.x;
    int d  = threadIdx.x;
    int b  = gp / LL;
    int l  = gp - b * LL;
    int h  = l / WW;
    int w  = l - h * WW;
    float acc = bc[d];
#pragma unroll
    for (int dy = -1; dy <= 1; dy++) {
        int hh = h + dy;
        if (hh < 0 || hh >= HH) continue;
#pragma unroll
        for (int dx = -1; dx <= 1; dx++) {
            int ww = w + dx;
            if (ww < 0 || ww >= WW) continue;
            acc = fmaf(xp[((size_t)b * LL + hh * WW + ww) * DIN + d],
                       Wc[d * 9 + (dy + 1) * 3 + (dx + 1)], acc);
        }
    }
    xi[(size_t)gp * DIN + d] = silu(acc);
}

// ------- kernel 3: x-proj -> dr (rank-6), B, C ------------------------------
constexpr int K3_PIX = 32;
__global__ __launch_bounds__(256) void k_xproj(
        const float* __restrict__ xi, const float* __restrict__ Wt,
        float* __restrict__ drbuf, float* __restrict__ Bbuf,
        float* __restrict__ Cbuf) {
    __shared__ float4 v4[K3_PIX][49];    // 25.1 KB, pad: bank=(4p+4j)%32
    __shared__ float4 sw4[EPROJ][49];    // 29.8 KB, pad: bank=(4e+4j)%32
    int k   = blockIdx.y;
    int gp0 = blockIdx.x * K3_PIX;
    int b   = gp0 / LL;
    int l0  = gp0 - b * LL;
    int t   = threadIdx.x;
    const float4* xin4 = (const float4*)(xi + (size_t)gp0 * DIN);
    for (int i = t; i < K3_PIX * 48; i += 256)
        v4[i / 48][i % 48] = xin4[i];
    const float4* wt4 = (const float4*)(Wt + (size_t)k * EPROJ * DIN);
    for (int i = t; i < EPROJ * 48; i += 256)
        sw4[i / 48][i % 48] = wt4[i];
    __syncthreads();
    int p0 = t & 15;            // pixel within 16-set
    int eg = t >> 4;            // e-group 0..15
    bool has3 = (eg < EPROJ - 32);      // eg < 6
    float acc[2][3] = {{0.f, 0.f, 0.f}, {0.f, 0.f, 0.f}};
    for (int j = 0; j < 48; j++) {
        float4 w0 = sw4[eg][j];
        float4 w1 = sw4[eg + 16][j];
        float4 w2 = has3 ? sw4[eg + 32][j] : make_float4(0.f, 0.f, 0.f, 0.f);
#pragma unroll
        for (int q = 0; q < 2; q++) {
            float4 vv = v4[p0 + 16 * q][j];
            acc[q][0] = fmaf(vv.x, w0.x, acc[q][0]); acc[q][0] = fmaf(vv.y, w0.y, acc[q][0]);
            acc[q][0] = fmaf(vv.z, w0.z, acc[q][0]); acc[q][0] = fmaf(vv.w, w0.w, acc[q][0]);
            acc[q][1] = fmaf(vv.x, w1.x, acc[q][1]); acc[q][1] = fmaf(vv.y, w1.y, acc[q][1]);
            acc[q][1] = fmaf(vv.z, w1.z, acc[q][1]); acc[q][1] = fmaf(vv.w, w1.w, acc[q][1]);
            acc[q][2] = fmaf(vv.x, w2.x, acc[q][2]); acc[q][2] = fmaf(vv.y, w2.y, acc[q][2]);
            acc[q][2] = fmaf(vv.z, w2.z, acc[q][2]); acc[q][2] = fmaf(vv.w, w2.w, acc[q][2]);
        }
    }
#pragma unroll
    for (int q = 0; q < 2; q++) {
        int p  = p0 + 16 * q;
        int ls = spatial_to_seq(k, l0 + p);
        size_t kb  = (size_t)(k * BATCH + b);
        size_t b8  = (kb * LL + ls) * 8;
        size_t b16 = (kb * LL + ls) * NST;
        if (eg < RNK) drbuf[b8 + eg] = acc[q][0];
        else          Bbuf[b16 + eg - RNK] = acc[q][0];
        int e1 = eg + 16;
        if (e1 < RNK + NST) Bbuf[b16 + e1 - RNK] = acc[q][1];
        else                Cbuf[b16 + e1 - RNK - NST] = acc[q][1];
        if (has3) Cbuf[b16 + eg + 32 - RNK - NST] = acc[q][2];
    }
}

// -------- kernel 4a: chunk-local scan -> per-chunk summary (P, h_end) --------
__global__ __launch_bounds__(256) void k_scanA(
        const float* __restrict__ xi, const float* __restrict__ drbuf,
        const float* __restrict__ Bbuf, const float* __restrict__ A_logs,
        const float* __restrict__ W_dt, const float* __restrict__ b_dt,
        float* __restrict__ Pbuf, float* __restrict__ hend) {
    __shared__ float2 sDU2[16][SCH + 2];   // [ch][s] {delta, delta*u}
    __shared__ float  sB1t[16][SCH + 4];   // [n][s]
    int c   = blockIdx.x;
    int blk = blockIdx.y;
    int k   = blk / (BATCH * CGRP);
    int rem = blk % (BATCH * CGRP);
    int b   = rem / CGRP;
    int cg  = rem % CGRP;
    int d0  = cg * 16;
    int t    = threadIdx.x;
    int lane = t & 63, wave = t >> 6;
    int grp  = lane >> 4, n = lane & 15;
    int ch   = wave * 4 + grp;
    int d    = d0 + ch;
    float A = -__expf(A_logs[((size_t)(k * DIN + d)) * NST + n]);
    size_t kb = (size_t)(k * BATCH + b);
    const float* drp = drbuf + kb * LL * 8;
    const float* bp  = Bbuf  + kb * LL * NST;
    const float* up  = xi    + (size_t)b * LL * DIN;
    int dloc = d0 + (t & 15);
    float bb = b_dt[k * DIN + dloc];
    float w0 = W_dt[((size_t)k * RNK + 0) * DIN + dloc];
    float w1 = W_dt[((size_t)k * RNK + 1) * DIN + dloc];
    float w2 = W_dt[((size_t)k * RNK + 2) * DIN + dloc];
    float w3 = W_dt[((size_t)k * RNK + 3) * DIN + dloc];
    float w4 = W_dt[((size_t)k * RNK + 4) * DIN + dloc];
    float w5 = W_dt[((size_t)k * RNK + 5) * DIN + dloc];
    int l0 = c * SCH;
    for (int i = t; i < SCH * 16; i += 256) {
        int s = i >> 4, cc = i & 15;
        int l = l0 + s;
        int lr = seq_to_lr(k, l);
        float4 r03 = *(const float4*)(drp + (size_t)l * 8);
        float2 r45 = *(const float2*)(drp + (size_t)l * 8 + 4);
        float raw = bb;
        raw = fmaf(r03.x, w0, raw); raw = fmaf(r03.y, w1, raw);
        raw = fmaf(r03.z, w2, raw); raw = fmaf(r03.w, w3, raw);
        raw = fmaf(r45.x, w4, raw); raw = fmaf(r45.y, w5, raw);
        float dlt = softplus_f(raw);
        float u = up[(size_t)lr * DIN + d0 + cc];
        sDU2[cc][s] = make_float2(dlt, dlt * u);
        sB1t[cc][s] = bp[(size_t)l * NST + cc];
    }
    __syncthreads();
    float h = 0.0f, P = 1.0f;
#pragma unroll 2
    for (int s4 = 0; s4 < SCH; s4 += 4) {
        float4 duA = *(const float4*)&sDU2[ch][s4];
        float4 duB = *(const float4*)&sDU2[ch][s4 + 2];
        float4 bq  = *(const float4*)&sB1t[n][s4];
        float dA;
        dA = __expf(duA.x * A); h = fmaf(dA, h, duA.y * bq.x); P *= dA;
        dA = __expf(duA.z * A); h = fmaf(dA, h, duA.w * bq.y); P *= dA;
        dA = __expf(duB.x * A); h = fmaf(dA, h, duB.y * bq.z); P *= dA;
        dA = __expf(duB.z * A); h = fmaf(dA, h, duB.w * bq.w); P *= dA;
    }
    size_t idx = hs_idx(c, (int)kb, d, n);
    Pbuf[idx] = P;
    hend[idx] = h;
}

// -------- kernel 4b: sequential combine over 49 chunk summaries --------------
__global__ __launch_bounds__(256) void k_scanB(
        const float* __restrict__ Pbuf, const float* __restrict__ hend,
        float* __restrict__ hin) {
    int tid = blockIdx.x * 256 + threadIdx.x;       // over K*B*DIN*NST = 24576
    int kb  = tid / (DIN * NST);
    int dn  = tid % (DIN * NST);
    float h = 0.0f;
    for (int c = 0; c < NCH; c++) {
        size_t idx = ((size_t)(c * (NK * BATCH) + kb)) * (DIN * NST) + dn;
        hin[idx] = h;
        h = fmaf(Pbuf[idx], h, hend[idx]);
    }
}

// -------- kernel 4c: chunk-local scan with true h_in; emit y (no atomics) ----
__global__ __launch_bounds__(256) void k_scanC(
        const float* __restrict__ xi, const float* __restrict__ drbuf,
        const float* __restrict__ Bbuf, const float* __restrict__ Cbuf,
        const float* __restrict__ A_logs, const float* __restrict__ W_dt,
        const float* __restrict__ b_dt, const float* __restrict__ hin,
        float* __restrict__ ydir) {
    __shared__ float2 sDU2[16][SCH + 2];   // [ch][s] {delta, delta*u}
    __shared__ float2 sBC2[16][SCH + 2];   // [n][s]  {B, C}
    __shared__ float  sY[16][SCH + 4];     // [ch][s]
    int c   = blockIdx.x;
    int blk = blockIdx.y;
    int k   = blk / (BATCH * CGRP);
    int rem = blk % (BATCH * CGRP);
    int b   = rem / CGRP;
    int cg  = rem % CGRP;
    int d0  = cg * 16;
    int t    = threadIdx.x;
    int lane = t & 63, wave = t >> 6;
    int grp  = lane >> 4, n = lane & 15;
    int ch   = wave * 4 + grp;
    int d    = d0 + ch;
    float A = -__expf(A_logs[((size_t)(k * DIN + d)) * NST + n]);
    size_t kb = (size_t)(k * BATCH + b);
    const float* drp = drbuf + kb * LL * 8;
    const float* bp  = Bbuf  + kb * LL * NST;
    const float* cp  = Cbuf  + kb * LL * NST;
    const float* up  = xi    + (size_t)b * LL * DIN;
    float*       yp  = ydir  + kb * LL * DIN;     // per-direction slice
    int dloc = d0 + (t & 15);
    float bb = b_dt[k * DIN + dloc];
    float w0 = W_dt[((size_t)k * RNK + 0) * DIN + dloc];
    float w1 = W_dt[((size_t)k * RNK + 1) * DIN + dloc];
    float w2 = W_dt[((size_t)k * RNK + 2) * DIN + dloc];
    float w3 = W_dt[((size_t)k * RNK + 3) * DIN + dloc];
    float w4 = W_dt[((size_t)k * RNK + 4) * DIN + dloc];
    float w5 = W_dt[((size_t)k * RNK + 5) * DIN + dloc];
    int l0 = c * SCH;
    for (int i = t; i < SCH * 16; i += 256) {
        int s = i >> 4, cc = i & 15;
        int l = l0 + s;
        int lr = seq_to_lr(k, l);
        float4 r03 = *(const float4*)(drp + (size_t)l * 8);
        float2 r45 = *(const float2*)(drp + (size_t)l * 8 + 4);
        float raw = bb;
        raw = fmaf(r03.x, w0, raw); raw = fmaf(r03.y, w1, raw);
        raw = fmaf(r03.z, w2, raw); raw = fmaf(r03.w, w3, raw);
        raw = fmaf(r45.x, w4, raw); raw = fmaf(r45.y, w5, raw);
        float dlt = softplus_f(raw);
        float u = up[(size_t)lr * DIN + d0 + cc];
        sDU2[cc][s] = make_float2(dlt, dlt * u);
        sBC2[cc][s] = make_float2(bp[(size_t)l * NST + cc],
                                  cp[(size_t)l * NST + cc]);
    }
    float h = hin[hs_idx(c, (int)kb, d, n)];
    __syncthreads();
#pragma unroll 2
    for (int s4 = 0; s4 < SCH; s4 += 4) {
        float4 duA = *(const float4*)&sDU2[ch][s4];
        float4 duB = *(const float4*)&sDU2[ch][s4 + 2];
        float4 bcA = *(const float4*)&sBC2[n][s4];
        float4 bcB = *(const float4*)&sBC2[n][s4 + 2];
        float dA, y0, y1, y2, y3;
        dA = __expf(duA.x * A); h = fmaf(dA, h, duA.y * bcA.x); y0 = row_reduce16(h * bcA.y);
        dA = __expf(duA.z * A); h = fmaf(dA, h, duA.w * bcA.z); y1 = row_reduce16(h * bcA.w);
        dA = __expf(duB.x * A); h = fmaf(dA, h, duB.y * bcB.x); y2 = row_reduce16(h * bcB.y);
        dA = __expf(duB.z * A); h = fmaf(dA, h, duB.w * bcB.z); y3 = row_reduce16(h * bcB.w);
        if (n == 0) *(float4*)&sY[ch][s4] = make_float4(y0, y1, y2, y3);
    }
    __syncthreads();
    for (int i = t; i < SCH * 16; i += 256) {
        int s = i >> 4, cc = i & 15;
        int lr = seq_to_lr(k, l0 + s);
        yp[(size_t)lr * DIN + d0 + cc] = sY[cc][s];
    }
}

// ------- kernel 5: gather 4 directions + D*u + gate + out-projection ---------
constexpr int K5_PIX = 8;
__global__ __launch_bounds__(192) void k_out(
        const float* __restrict__ ydir, const float* __restrict__ xi,
        const float* __restrict__ zbuf, const float* __restrict__ Ds,
        const float* __restrict__ W_out, float* __restrict__ out) {
    __shared__ float g[DIN][12];           // [dd][p] padded: aligned b128 reads
    __shared__ float so[CDIM][9];          // padded stores
    int gp0 = blockIdx.x * K5_PIX;
    int b   = gp0 / LL;
    int l0  = gp0 - b * LL;
    int t   = threadIdx.x;
    for (int i = t; i < K5_PIX * DIN; i += 192) {
        int p = i / DIN, dd = i % DIN;
        size_t off = (size_t)(gp0 + p) * DIN + dd;    // (b*LL+l)*DIN + dd
        float y = ydir[off] + ydir[SZ_PX + off]
                + ydir[2 * SZ_PX + off] + ydir[3 * SZ_PX + off];
        float dsum = Ds[dd] + Ds[DIN + dd] + Ds[2 * DIN + dd] + Ds[3 * DIN + dd];
        y = fmaf(xi[off], dsum, y);
        g[dd][p] = y * silu(zbuf[off]);
    }
    __syncthreads();
    int f    = t % CDIM;        // output feature
    int half = t / CDIM;        // 0 or 1: which 4 pixels
    float acc[4] = {0.f, 0.f, 0.f, 0.f};
#pragma unroll 4
    for (int dd = 0; dd < DIN; dd++) {
        float wv = W_out[dd * CDIM + f];
        float4 gv = *(const float4*)&g[dd][half * 4];
        acc[0] = fmaf(gv.x, wv, acc[0]);
        acc[1] = fmaf(gv.y, wv, acc[1]);
        acc[2] = fmaf(gv.z, wv, acc[2]);
        acc[3] = fmaf(gv.w, wv, acc[3]);
    }
#pragma unroll
    for (int p = 0; p < 4; p++) so[f][half * 4 + p] = acc[p];
    __syncthreads();
    for (int i = t; i < CDIM * K5_PIX; i += 192) {
        int f2 = i / K5_PIX, p2 = i % K5_PIX;
        out[((size_t)(b * CDIM + f2)) * LL + l0 + p2] = so[f2][p2];
    }
}

// ---------------- launch ----------------------------------------------------
extern "C" void kernel_launch(void* const* d_in, const int* in_sizes, int n_in,
                              void* d_out, int out_size, void* d_ws, size_t ws_size,
                              hipStream_t stream) {
    const float* x       = (const float*)d_in[0];
    const float* W_in    = (const float*)d_in[1];
    const float* W_conv  = (const float*)d_in[2];
    const float* b_conv  = (const float*)d_in[3];
    const float* W_xproj = (const float*)d_in[4];
    const float* W_dt    = (const float*)d_in[5];
    const float* b_dt    = (const float*)d_in[6];
    const float* A_logs  = (const float*)d_in[7];
    const float* Ds      = (const float*)d_in[8];
    const float* W_out   = (const float*)d_in[9];
    float* out = (float*)d_out;
    float* ws  = (float*)d_ws;

    float* xp    = ws + OFF_XP;      // dead after k_conv; reused as Pbuf
    float* z     = ws + OFF_Z;
    float* xi    = ws + OFF_XI;
    float* drbuf = ws + OFF_DR;
    float* Bbuf  = ws + OFF_B;
    float* Cbuf  = ws + OFF_C;
    float* ydir  = ws + OFF_YD;
    float* hend  = ws + OFF_HE;
    float* hin   = ws + OFF_HI;
    float* Wt    = ws + OFF_WT;
    float* Pbuf  = xp;

    k_inproj<<<(BATCH * LL) / K1_PIX, 384, 0, stream>>>(x, W_in, W_xproj, xp, z, Wt);
    k_conv<<<BATCH * LL, DIN, 0, stream>>>(xp, W_conv, b_conv, xi);
    dim3 g3((BATCH * LL) / K3_PIX, NK);
    k_xproj<<<g3, 256, 0, stream>>>(xi, Wt, drbuf, Bbuf, Cbuf);
    dim3 gs(NCH, NK * BATCH * CGRP);
    k_scanA<<<gs, 256, 0, stream>>>(xi, drbuf, Bbuf, A_logs, W_dt, b_dt, Pbuf, hend);
    k_scanB<<<(NK * BATCH * DIN * NST) / 256, 256, 0, stream>>>(Pbuf, hend, hin);
    k_scanC<<<gs, 256, 0, stream>>>(xi, drbuf, Bbuf, Cbuf, A_logs, W_dt, b_dt, hin, ydir);
    k_out<<<(BATCH * LL) / K5_PIX, 192, 0, stream>>>(ydir, xi, z, Ds, W_out, out);
}

// Round 9
// 207.631 us; speedup vs baseline: 1.3382x; 1.0049x over previous
//
#include <hip/hip_runtime.h>
#include <math.h>

// ---------------- problem constants ----------------
constexpr int BATCH  = 2;
constexpr int CDIM   = 96;    // model dim
constexpr int HH     = 56;
constexpr int WW     = 56;
constexpr int LL     = HH * WW;          // 3136
constexpr int DIN    = 192;              // d_inner
constexpr int NK     = 4;                // directions
constexpr int NST    = 16;               // d_state
constexpr int RNK    = 6;                // dt_rank
constexpr int EPROJ  = RNK + 2 * NST;    // 38
constexpr int SCH    = 64;               // steps per scan chunk
constexpr int NCH    = LL / SCH;         // 49 chunks
constexpr int CGRP   = DIN / 16;         // 12 channel-groups of 16

// LDS strides (derived for 16B alignment + <=2-way banks)
constexpr int STDU = SCH + 2;   // float2 rows, stride 66
constexpr int STBC = SCH + 6;   // float2 rows, stride 70
constexpr int STY  = SCH + 4;   // float  rows, stride 68
constexpr int STB1 = SCH + 4;   // float  rows, stride 68

// workspace layout (floats)
constexpr size_t SZ_PX   = (size_t)BATCH * LL * DIN;        // 1,204,224
constexpr size_t OFF_XP  = 0;                               // xp; reused as Pbuf
constexpr size_t OFF_Z   = OFF_XP + SZ_PX;
constexpr size_t OFF_XI  = OFF_Z  + SZ_PX;
constexpr size_t OFF_DR  = OFF_XI + SZ_PX;                  // dr: [kb][L][8]
constexpr size_t SZ_DR   = (size_t)NK * BATCH * LL * 8;
constexpr size_t OFF_B   = OFF_DR + SZ_DR;                  // B: K*B*L*16
constexpr size_t SZ_BC   = (size_t)NK * BATCH * LL * NST;
constexpr size_t OFF_C   = OFF_B + SZ_BC;
constexpr size_t OFF_YD  = OFF_C + SZ_BC;                   // ydir: [k][b][sp][d]
constexpr size_t SZ_YD   = (size_t)NK * BATCH * LL * DIN;   // 4,816,896
constexpr size_t OFF_HE  = OFF_YD + SZ_YD;                  // h_end per chunk
constexpr size_t SZ_HS   = (size_t)NK * BATCH * NCH * DIN * NST;
constexpr size_t OFF_HI  = OFF_HE + SZ_HS;                  // h_in  per chunk
constexpr size_t OFF_WT  = OFF_HI + SZ_HS;                  // Wt: [k][e][d]
constexpr size_t SZ_WT   = (size_t)NK * EPROJ * DIN;        // 29,184

__device__ __forceinline__ float silu(float v) {
    return v / (1.0f + __expf(-v));
}

__device__ __forceinline__ float softplus_f(float x) {
    return (x > 20.0f) ? x : __logf(1.0f + __expf(x));
}

// full 16-lane-row sum via DPP row rotations (VALU only, no LDS pipe).
__device__ __forceinline__ float row_reduce16(float p) {
    p += __int_as_float(__builtin_amdgcn_update_dpp(0, __float_as_int(p), 0x128, 0xf, 0xf, true));
    p += __int_as_float(__builtin_amdgcn_update_dpp(0, __float_as_int(p), 0x124, 0xf, 0xf, true));
    p += __int_as_float(__builtin_amdgcn_update_dpp(0, __float_as_int(p), 0x122, 0xf, 0xf, true));
    p += __int_as_float(__builtin_amdgcn_update_dpp(0, __float_as_int(p), 0x121, 0xf, 0xf, true));
    return p;
}

// direction k, sequence position l -> row-major spatial index
__device__ __forceinline__ int seq_to_lr(int k, int l) {
    int q = l / WW;
    int r = l - q * WW;
    if (k == 0) return l;
    if (k == 1) return q * WW + (WW - 1 - r);
    if (k == 2) return r * WW + q;
    return (WW - 1 - r) * WW + q;
}

// direction k, row-major spatial index s -> sequence position (inverse map)
__device__ __forceinline__ int spatial_to_seq(int k, int s) {
    int h = s / WW;
    int w = s - h * WW;
    if (k == 0) return s;
    if (k == 1) return h * WW + (WW - 1 - w);
    if (k == 2) return w * WW + h;
    return w * WW + (WW - 1 - h);
}

// chunk-summary index: [c][kb][d][n]
__device__ __forceinline__ size_t hs_idx(int c, int kb, int d, int n) {
    return ((size_t)(c * (NK * BATCH) + kb) * DIN + d) * NST + n;
}

// rank-6 delta: vectorized over 4 consecutive d (components of float4)
__device__ __forceinline__ float4 delta4(
        float4 r03, float2 r45, const float4* wr, float4 bb4) {
    float4 raw = bb4;
    raw.x = fmaf(r03.x, wr[0].x, raw.x); raw.y = fmaf(r03.x, wr[0].y, raw.y);
    raw.z = fmaf(r03.x, wr[0].z, raw.z); raw.w = fmaf(r03.x, wr[0].w, raw.w);
    raw.x = fmaf(r03.y, wr[1].x, raw.x); raw.y = fmaf(r03.y, wr[1].y, raw.y);
    raw.z = fmaf(r03.y, wr[1].z, raw.z); raw.w = fmaf(r03.y, wr[1].w, raw.w);
    raw.x = fmaf(r03.z, wr[2].x, raw.x); raw.y = fmaf(r03.z, wr[2].y, raw.y);
    raw.z = fmaf(r03.z, wr[2].z, raw.z); raw.w = fmaf(r03.z, wr[2].w, raw.w);
    raw.x = fmaf(r03.w, wr[3].x, raw.x); raw.y = fmaf(r03.w, wr[3].y, raw.y);
    raw.z = fmaf(r03.w, wr[3].z, raw.z); raw.w = fmaf(r03.w, wr[3].w, raw.w);
    raw.x = fmaf(r45.x, wr[4].x, raw.x); raw.y = fmaf(r45.x, wr[4].y, raw.y);
    raw.z = fmaf(r45.x, wr[4].z, raw.z); raw.w = fmaf(r45.x, wr[4].w, raw.w);
    raw.x = fmaf(r45.y, wr[5].x, raw.x); raw.y = fmaf(r45.y, wr[5].y, raw.y);
    raw.z = fmaf(r45.y, wr[5].z, raw.z); raw.w = fmaf(r45.y, wr[5].w, raw.w);
    raw.x = softplus_f(raw.x); raw.y = softplus_f(raw.y);
    raw.z = softplus_f(raw.z); raw.w = softplus_f(raw.w);
    return raw;
}

// ---------------- kernel 1: in-projection (x^T @ W_in -> xp, z) --------------
// Side job: first threads also transpose W_xproj -> Wt[k][e][d].
constexpr int K1_PIX = 8;
__global__ __launch_bounds__(384) void k_inproj(
        const float* __restrict__ x, const float* __restrict__ W_in,
        const float* __restrict__ W_xproj,
        float* __restrict__ xp, float* __restrict__ z, float* __restrict__ Wt) {
    __shared__ float sxT[CDIM][K1_PIX];   // [c][p], 3 KB
    int gp0 = blockIdx.x * K1_PIX;      // global pixel = b*LL + l
    int t   = threadIdx.x;
    int b   = gp0 / LL;
    int l0  = gp0 - b * LL;
    int gid = blockIdx.x * 384 + t;
    if (gid < NK * DIN * EPROJ) {
        int k = gid / (DIN * EPROJ);
        int r = gid % (DIN * EPROJ);
        int d = r / EPROJ;
        int e = r % EPROJ;
        Wt[((size_t)k * EPROJ + e) * DIN + d] = W_xproj[gid];
    }
    for (int i = t; i < CDIM * K1_PIX; i += 384) {
        int c = i >> 3, p = i & 7;
        sxT[c][p] = x[((size_t)(b * CDIM + c)) * LL + l0 + p];
    }
    __syncthreads();
    int e = t;                          // 0..383 output feature
    float acc[K1_PIX];
#pragma unroll
    for (int p = 0; p < K1_PIX; p++) acc[p] = 0.0f;
    const float4* sx4 = (const float4*)sxT;
#pragma unroll 4
    for (int c = 0; c < CDIM; c++) {
        float w  = W_in[c * (2 * DIN) + e];
        float4 va = sx4[2 * c];
        float4 vb = sx4[2 * c + 1];
        acc[0] = fmaf(va.x, w, acc[0]); acc[1] = fmaf(va.y, w, acc[1]);
        acc[2] = fmaf(va.z, w, acc[2]); acc[3] = fmaf(va.w, w, acc[3]);
        acc[4] = fmaf(vb.x, w, acc[4]); acc[5] = fmaf(vb.y, w, acc[5]);
        acc[6] = fmaf(vb.z, w, acc[6]); acc[7] = fmaf(vb.w, w, acc[7]);
    }
    if (e < DIN) {
#pragma unroll
        for (int p = 0; p < K1_PIX; p++)
            xp[((size_t)(gp0 + p)) * DIN + e] = acc[p];
    } else {
        int e2 = e - DIN;
#pragma unroll
        for (int p = 0; p < K1_PIX; p++)
            z[((size_t)(gp0 + p)) * DIN + e2] = acc[p];
    }
}

// ---------------- kernel 2: depthwise conv 3x3 + bias + SiLU ----------------
__global__ __launch_bounds__(192) void k_conv(
        const float* __restrict__ xp, const float* __restrict__ Wc,
        const float* __restrict__ bc, float* __restrict__ xi) {
    int gp = blockIdx.x;
    int d  = threadIdx.x;
    int b  = gp / LL;
    int l  = gp - b * LL;
    int h  = l / WW;
    int w  = l - h * WW;
    float acc = bc[d];
#pragma unroll
    for (int dy = -1; dy <= 1; dy++) {
        int hh = h + dy;
        if (hh < 0 || hh >= HH) continue;
#pragma unroll
        for (int dx = -1; dx <= 1; dx++) {
            int ww = w + dx;
            if (ww < 0 || ww >= WW) continue;
            acc = fmaf(xp[((size_t)b * LL + hh * WW + ww) * DIN + d],
                       Wc[d * 9 + (dy + 1) * 3 + (dx + 1)], acc);
        }
    }
    xi[(size_t)gp * DIN + d] = silu(acc);
}

// ------- kernel 3: x-proj -> dr (rank-6), B, C ------------------------------
constexpr int K3_PIX = 32;
__global__ __launch_bounds__(256) void k_xproj(
        const float* __restrict__ xi, const float* __restrict__ Wt,
        float* __restrict__ drbuf, float* __restrict__ Bbuf,
        float* __restrict__ Cbuf) {
    __shared__ float4 v4[K3_PIX][49];    // 25.1 KB
    __shared__ float4 sw4[EPROJ][49];    // 29.8 KB
    int k   = blockIdx.y;
    int gp0 = blockIdx.x * K3_PIX;
    int b   = gp0 / LL;
    int l0  = gp0 - b * LL;
    int t   = threadIdx.x;
    const float4* xin4 = (const float4*)(xi + (size_t)gp0 * DIN);
    for (int i = t; i < K3_PIX * 48; i += 256)
        v4[i / 48][i % 48] = xin4[i];
    const float4* wt4 = (const float4*)(Wt + (size_t)k * EPROJ * DIN);
    for (int i = t; i < EPROJ * 48; i += 256)
        sw4[i / 48][i % 48] = wt4[i];
    __syncthreads();
    int p0 = t & 15;            // pixel within 16-set
    int eg = t >> 4;            // e-group 0..15
    bool has3 = (eg < EPROJ - 32);      // eg < 6
    float acc[2][3] = {{0.f, 0.f, 0.f}, {0.f, 0.f, 0.f}};
    for (int j = 0; j < 48; j++) {
        float4 w0 = sw4[eg][j];
        float4 w1 = sw4[eg + 16][j];
        float4 w2 = has3 ? sw4[eg + 32][j] : make_float4(0.f, 0.f, 0.f, 0.f);
#pragma unroll
        for (int q = 0; q < 2; q++) {
            float4 vv = v4[p0 + 16 * q][j];
            acc[q][0] = fmaf(vv.x, w0.x, acc[q][0]); acc[q][0] = fmaf(vv.y, w0.y, acc[q][0]);
            acc[q][0] = fmaf(vv.z, w0.z, acc[q][0]); acc[q][0] = fmaf(vv.w, w0.w, acc[q][0]);
            acc[q][1] = fmaf(vv.x, w1.x, acc[q][1]); acc[q][1] = fmaf(vv.y, w1.y, acc[q][1]);
            acc[q][1] = fmaf(vv.z, w1.z, acc[q][1]); acc[q][1] = fmaf(vv.w, w1.w, acc[q][1]);
            acc[q][2] = fmaf(vv.x, w2.x, acc[q][2]); acc[q][2] = fmaf(vv.y, w2.y, acc[q][2]);
            acc[q][2] = fmaf(vv.z, w2.z, acc[q][2]); acc[q][2] = fmaf(vv.w, w2.w, acc[q][2]);
        }
    }
#pragma unroll
    for (int q = 0; q < 2; q++) {
        int p  = p0 + 16 * q;
        int ls = spatial_to_seq(k, l0 + p);
        size_t kb  = (size_t)(k * BATCH + b);
        size_t b8  = (kb * LL + ls) * 8;
        size_t b16 = (kb * LL + ls) * NST;
        if (eg < RNK) drbuf[b8 + eg] = acc[q][0];
        else          Bbuf[b16 + eg - RNK] = acc[q][0];
        int e1 = eg + 16;
        if (e1 < RNK + NST) Bbuf[b16 + e1 - RNK] = acc[q][1];
        else                Cbuf[b16 + e1 - RNK - NST] = acc[q][1];
        if (has3) Cbuf[b16 + eg + 32 - RNK - NST] = acc[q][2];
    }
}

// -------- kernel 4a: chunk-local scan -> per-chunk summary (P, h_end) --------
// Staging: thread (s = t>>2, cc0 = (t&3)*4) loads float4s for 4 contiguous cc.
__global__ __launch_bounds__(256) void k_scanA(
        const float* __restrict__ xi, const float* __restrict__ drbuf,
        const float* __restrict__ Bbuf, const float* __restrict__ A_logs,
        const float* __restrict__ W_dt, const float* __restrict__ b_dt,
        float* __restrict__ Pbuf, float* __restrict__ hend) {
    __shared__ float2 sDU2[16][STDU];   // [ch][s] {delta, delta*u}
    __shared__ float  sB1t[16][STB1];   // [n][s]
    int c   = blockIdx.x;
    int blk = blockIdx.y;
    int k   = blk / (BATCH * CGRP);
    int rem = blk % (BATCH * CGRP);
    int b   = rem / CGRP;
    int cg  = rem % CGRP;
    int d0  = cg * 16;
    int t    = threadIdx.x;
    int lane = t & 63, wave = t >> 6;
    int grp  = lane >> 4, n = lane & 15;
    int ch   = wave * 4 + grp;
    int d    = d0 + ch;
    float A = -__expf(A_logs[((size_t)(k * DIN + d)) * NST + n]);
    size_t kb = (size_t)(k * BATCH + b);
    const float* drp = drbuf + kb * LL * 8;
    const float* bp  = Bbuf  + kb * LL * NST;
    const float* up  = xi    + (size_t)b * LL * DIN;
    // staging identity
    int ss  = t >> 2;            // 0..63
    int cc0 = (t & 3) * 4;       // 0,4,8,12
    float4 wr[RNK];
#pragma unroll
    for (int r = 0; r < RNK; r++)
        wr[r] = *(const float4*)(W_dt + ((size_t)k * RNK + r) * DIN + d0 + cc0);
    float4 bb4 = *(const float4*)(b_dt + k * DIN + d0 + cc0);
    int l0 = c * SCH;
    {
        int l  = l0 + ss;
        int lr = seq_to_lr(k, l);
        float4 r03 = *(const float4*)(drp + (size_t)l * 8);
        float2 r45 = *(const float2*)(drp + (size_t)l * 8 + 4);
        float4 dlt = delta4(r03, r45, wr, bb4);
        float4 u4  = *(const float4*)(up + (size_t)lr * DIN + d0 + cc0);
        float4 B4  = *(const float4*)(bp + (size_t)l * NST + cc0);
        sDU2[cc0 + 0][ss] = make_float2(dlt.x, dlt.x * u4.x);
        sDU2[cc0 + 1][ss] = make_float2(dlt.y, dlt.y * u4.y);
        sDU2[cc0 + 2][ss] = make_float2(dlt.z, dlt.z * u4.z);
        sDU2[cc0 + 3][ss] = make_float2(dlt.w, dlt.w * u4.w);
        sB1t[cc0 + 0][ss] = B4.x;
        sB1t[cc0 + 1][ss] = B4.y;
        sB1t[cc0 + 2][ss] = B4.z;
        sB1t[cc0 + 3][ss] = B4.w;
    }
    __syncthreads();
    float h = 0.0f, P = 1.0f;
#pragma unroll 2
    for (int s4 = 0; s4 < SCH; s4 += 4) {
        float4 duA = *(const float4*)&sDU2[ch][s4];
        float4 duB = *(const float4*)&sDU2[ch][s4 + 2];
        float4 bq  = *(const float4*)&sB1t[n][s4];
        float dA;
        dA = __expf(duA.x * A); h = fmaf(dA, h, duA.y * bq.x); P *= dA;
        dA = __expf(duA.z * A); h = fmaf(dA, h, duA.w * bq.y); P *= dA;
        dA = __expf(duB.x * A); h = fmaf(dA, h, duB.y * bq.z); P *= dA;
        dA = __expf(duB.z * A); h = fmaf(dA, h, duB.w * bq.w); P *= dA;
    }
    size_t idx = hs_idx(c, (int)kb, d, n);
    Pbuf[idx] = P;
    hend[idx] = h;
}

// -------- kernel 4b: sequential combine over 49 chunk summaries --------------
__global__ __launch_bounds__(256) void k_scanB(
        const float* __restrict__ Pbuf, const float* __restrict__ hend,
        float* __restrict__ hin) {
    int tid = blockIdx.x * 256 + threadIdx.x;       // over K*B*DIN*NST = 24576
    int kb  = tid / (DIN * NST);
    int dn  = tid % (DIN * NST);
    float h = 0.0f;
    for (int c = 0; c < NCH; c++) {
        size_t idx = ((size_t)(c * (NK * BATCH) + kb)) * (DIN * NST) + dn;
        hin[idx] = h;
        h = fmaf(Pbuf[idx], h, hend[idx]);
    }
}

// -------- kernel 4c: chunk-local scan with true h_in; emit y (no atomics) ----
__global__ __launch_bounds__(256) void k_scanC(
        const float* __restrict__ xi, const float* __restrict__ drbuf,
        const float* __restrict__ Bbuf, const float* __restrict__ Cbuf,
        const float* __restrict__ A_logs, const float* __restrict__ W_dt,
        const float* __restrict__ b_dt, const float* __restrict__ hin,
        float* __restrict__ ydir) {
    __shared__ float2 sDU2[16][STDU];   // [ch][s] {delta, delta*u}
    __shared__ float2 sBC2[16][STBC];   // [n][s]  {B, C}
    __shared__ float  sY[16][STY];      // [ch][s]
    int c   = blockIdx.x;
    int blk = blockIdx.y;
    int k   = blk / (BATCH * CGRP);
    int rem = blk % (BATCH * CGRP);
    int b   = rem / CGRP;
    int cg  = rem % CGRP;
    int d0  = cg * 16;
    int t    = threadIdx.x;
    int lane = t & 63, wave = t >> 6;
    int grp  = lane >> 4, n = lane & 15;
    int ch   = wave * 4 + grp;
    int d    = d0 + ch;
    float A = -__expf(A_logs[((size_t)(k * DIN + d)) * NST + n]);
    size_t kb = (size_t)(k * BATCH + b);
    const float* drp = drbuf + kb * LL * 8;
    const float* bp  = Bbuf  + kb * LL * NST;
    const float* cp  = Cbuf  + kb * LL * NST;
    const float* up  = xi    + (size_t)b * LL * DIN;
    float*       yp  = ydir  + kb * LL * DIN;     // per-direction slice
    int ss  = t >> 2;
    int cc0 = (t & 3) * 4;
    float4 wr[RNK];
#pragma unroll
    for (int r = 0; r < RNK; r++)
        wr[r] = *(const float4*)(W_dt + ((size_t)k * RNK + r) * DIN + d0 + cc0);
    float4 bb4 = *(const float4*)(b_dt + k * DIN + d0 + cc0);
    int l0 = c * SCH;
    {
        int l  = l0 + ss;
        int lr = seq_to_lr(k, l);
        float4 r03 = *(const float4*)(drp + (size_t)l * 8);
        float2 r45 = *(const float2*)(drp + (size_t)l * 8 + 4);
        float4 dlt = delta4(r03, r45, wr, bb4);
        float4 u4  = *(const float4*)(up + (size_t)lr * DIN + d0 + cc0);
        float4 B4  = *(const float4*)(bp + (size_t)l * NST + cc0);
        float4 C4  = *(const float4*)(cp + (size_t)l * NST + cc0);
        sDU2[cc0 + 0][ss] = make_float2(dlt.x, dlt.x * u4.x);
        sDU2[cc0 + 1][ss] = make_float2(dlt.y, dlt.y * u4.y);
        sDU2[cc0 + 2][ss] = make_float2(dlt.z, dlt.z * u4.z);
        sDU2[cc0 + 3][ss] = make_float2(dlt.w, dlt.w * u4.w);
        sBC2[cc0 + 0][ss] = make_float2(B4.x, C4.x);
        sBC2[cc0 + 1][ss] = make_float2(B4.y, C4.y);
        sBC2[cc0 + 2][ss] = make_float2(B4.z, C4.z);
        sBC2[cc0 + 3][ss] = make_float2(B4.w, C4.w);
    }
    float h = hin[hs_idx(c, (int)kb, d, n)];
    __syncthreads();
#pragma unroll 2
    for (int s4 = 0; s4 < SCH; s4 += 4) {
        float4 duA = *(const float4*)&sDU2[ch][s4];
        float4 duB = *(const float4*)&sDU2[ch][s4 + 2];
        float4 bcA = *(const float4*)&sBC2[n][s4];
        float4 bcB = *(const float4*)&sBC2[n][s4 + 2];
        float dA, y0, y1, y2, y3;
        dA = __expf(duA.x * A); h = fmaf(dA, h, duA.y * bcA.x); y0 = row_reduce16(h * bcA.y);
        dA = __expf(duA.z * A); h = fmaf(dA, h, duA.w * bcA.z); y1 = row_reduce16(h * bcA.w);
        dA = __expf(duB.x * A); h = fmaf(dA, h, duB.y * bcB.x); y2 = row_reduce16(h * bcB.y);
        dA = __expf(duB.z * A); h = fmaf(dA, h, duB.w * bcB.z); y3 = row_reduce16(h * bcB.w);
        if (n == 0) *(float4*)&sY[ch][s4] = make_float4(y0, y1, y2, y3);
    }
    __syncthreads();
    for (int i = t; i < SCH * 16; i += 256) {
        int s = i >> 4, cc = i & 15;
        int lr = seq_to_lr(k, l0 + s);
        yp[(size_t)lr * DIN + d0 + cc] = sY[cc][s];
    }
}

// ------- kernel 5: gather 4 directions + D*u + gate + out-projection ---------
constexpr int K5_PIX = 8;
__global__ __launch_bounds__(192) void k_out(
        const float* __restrict__ ydir, const float* __restrict__ xi,
        const float* __restrict__ zbuf, const float* __restrict__ Ds,
        const float* __restrict__ W_out, float* __restrict__ out) {
    __shared__ float g[DIN][12];           // [dd][p] padded
    __shared__ float so[CDIM][9];          // padded stores
    int gp0 = blockIdx.x * K5_PIX;
    int b   = gp0 / LL;
    int l0  = gp0 - b * LL;
    int t   = threadIdx.x;
    for (int i = t; i < K5_PIX * DIN; i += 192) {
        int p = i / DIN, dd = i % DIN;
        size_t off = (size_t)(gp0 + p) * DIN + dd;
        float y = ydir[off] + ydir[SZ_PX + off]
                + ydir[2 * SZ_PX + off] + ydir[3 * SZ_PX + off];
        float dsum = Ds[dd] + Ds[DIN + dd] + Ds[2 * DIN + dd] + Ds[3 * DIN + dd];
        y = fmaf(xi[off], dsum, y);
        g[dd][p] = y * silu(zbuf[off]);
    }
    __syncthreads();
    int f    = t % CDIM;
    int half = t / CDIM;
    float acc[4] = {0.f, 0.f, 0.f, 0.f};
#pragma unroll 4
    for (int dd = 0; dd < DIN; dd++) {
        float wv = W_out[dd * CDIM + f];
        float4 gv = *(const float4*)&g[dd][half * 4];
        acc[0] = fmaf(gv.x, wv, acc[0]);
        acc[1] = fmaf(gv.y, wv, acc[1]);
        acc[2] = fmaf(gv.z, wv, acc[2]);
        acc[3] = fmaf(gv.w, wv, acc[3]);
    }
#pragma unroll
    for (int p = 0; p < 4; p++) so[f][half * 4 + p] = acc[p];
    __syncthreads();
    for (int i = t; i < CDIM * K5_PIX; i += 192) {
        int f2 = i / K5_PIX, p2 = i % K5_PIX;
        out[((size_t)(b * CDIM + f2)) * LL + l0 + p2] = so[f2][p2];
    }
}

// ---------------- launch ----------------------------------------------------
extern "C" void kernel_launch(void* const* d_in, const int* in_sizes, int n_in,
                              void* d_out, int out_size, void* d_ws, size_t ws_size,
                              hipStream_t stream) {
    const float* x       = (const float*)d_in[0];
    const float* W_in    = (const float*)d_in[1];
    const float* W_conv  = (const float*)d_in[2];
    const float* b_conv  = (const float*)d_in[3];
    const float* W_xproj = (const float*)d_in[4];
    const float* W_dt    = (const float*)d_in[5];
    const float* b_dt    = (const float*)d_in[6];
    const float* A_logs  = (const float*)d_in[7];
    const float* Ds      = (const float*)d_in[8];
    const float* W_out   = (const float*)d_in[9];
    float* out = (float*)d_out;
    float* ws  = (float*)d_ws;

    float* xp    = ws + OFF_XP;      // dead after k_conv; reused as Pbuf
    float* z     = ws + OFF_Z;
    float* xi    = ws + OFF_XI;
    float* drbuf = ws + OFF_DR;
    float* Bbuf  = ws + OFF_B;
    float* Cbuf  = ws + OFF_C;
    float* ydir  = ws + OFF_YD;
    float* hend  = ws + OFF_HE;
    float* hin   = ws + OFF_HI;
    float* Wt    = ws + OFF_WT;
    float* Pbuf  = xp;

    k_inproj<<<(BATCH * LL) / K1_PIX, 384, 0, stream>>>(x, W_in, W_xproj, xp, z, Wt);
    k_conv<<<BATCH * LL, DIN, 0, stream>>>(xp, W_conv, b_conv, xi);
    dim3 g3((BATCH * LL) / K3_PIX, NK);
    k_xproj<<<g3, 256, 0, stream>>>(xi, Wt, drbuf, Bbuf, Cbuf);
    dim3 gs(NCH, NK * BATCH * CGRP);
    k_scanA<<<gs, 256, 0, stream>>>(xi, drbuf, Bbuf, A_logs, W_dt, b_dt, Pbuf, hend);
    k_scanB<<<(NK * BATCH * DIN * NST) / 256, 256, 0, stream>>>(Pbuf, hend, hin);
    k_scanC<<<gs, 256, 0, stream>>>(xi, drbuf, Bbuf, Cbuf, A_logs, W_dt, b_dt, hin, ydir);
    k_out<<<(BATCH * LL) / K5_PIX, 192, 0, stream>>>(ydir, xi, z, Ds, W_out, out);
}